// Round 14
// baseline (379.736 us; speedup 1.0000x reference)
//
#include <hip/hip_runtime.h>

typedef __attribute__((ext_vector_type(4))) float f32x4;
typedef __attribute__((ext_vector_type(8))) short short8;
typedef __attribute__((ext_vector_type(2))) unsigned uint2e;

#define DEV static __device__ __forceinline__

DEV ushort f2b(float f) {
  union { float f; unsigned u; } v; v.f = f;
  unsigned r = v.u + 0x7FFF + ((v.u >> 16) & 1);
  return (ushort)(r >> 16);
}
DEV unsigned pack_bf2(float lo, float hi) {
  return (unsigned)f2b(lo) | ((unsigned)f2b(hi) << 16);
}
DEV float bflo(unsigned p) { return __uint_as_float(p << 16); }
DEV float bfhi(unsigned p) { return __uint_as_float(p & 0xFFFF0000u); }
DEV float b2f(ushort u) { return __uint_as_float((unsigned)u << 16); }

// raw v_exp_f32 (2^x), no OCML denorm fixup sequence
DEV float fexp2(float x) { float r; asm("v_exp_f32 %0, %1" : "=v"(r) : "v"(x)); return r; }

// lanes 0-31 get s[lane] + s[lane+32] (hi lanes garbage — callers use lanes <8)
DEV float xor32_add_lo(float s) {
  uint2e r = __builtin_amdgcn_permlane32_swap(__float_as_uint(s), __float_as_uint(s), false, false);
  return s + __uint_as_float(r.x);
}

// DPP helpers (quad_perm / row_ror / row_bcast) and ds_swizzle xor
#define QP(x, ctrl) __int_as_float(__builtin_amdgcn_update_dpp(0, __float_as_int(x), (ctrl), 0xf, 0xf, false))
#define SWZ(x, off) __int_as_float(__builtin_amdgcn_ds_swizzle(__float_as_int(x), (off)))
#define DPP_ADD(x, ctrl, rmask) \
  ((x) + __int_as_float(__builtin_amdgcn_update_dpp(0, __float_as_int(x), (ctrl), (rmask), 0xf, false)))

#define LOG2E 1.44269504f

// ---------------------------------------------------------------- constants
#define BB    2
#define LL    2048
#define DD    512
#define HH    8
#define EE    64
#define DIN   1024
#define NS    64
#define RR    32
#define BL    4096            // B*L
#define NCH   16              // scan chunks
#define TC    128             // steps per chunk (LL/NCH)
#define NC    1536            // comb width (ctx | ym)
#define NQ    3584            // merged qkv+xz width
#define XOFF  1536            // x_in column offset in merged buffer
#define ZOFF  2560            // z column offset
#define MFMA(a,b,c) __builtin_amdgcn_mfma_f32_16x16x32_bf16((a),(b),(c),0,0,0)

// ---------------------------------------------------------------- f32 -> bf16 multi-convert
struct CvtJobs {
  const float* src[7];
  ushort*      dst[7];
  int          n[7];
};

__global__ __launch_bounds__(256) void cvt_multi(CvtJobs j) {
  int job = blockIdx.y;
  const float* s = j.src[job];
  ushort* d = j.dst[job];
  int n = j.n[job];
  for (int i = blockIdx.x * 256 + threadIdx.x; i < n; i += gridDim.x * 256)
    d[i] = f2b(s[i]);
}

// ---------------------------------------------------------------- pack combined [wo | out_proj] weight + merged bias
__global__ __launch_bounds__(256) void pack_wcomb(
    const float* __restrict__ wo, const float* __restrict__ opw,
    const float* __restrict__ bq, const float* __restrict__ bk,
    const float* __restrict__ bv, ushort* __restrict__ wc,
    float* __restrict__ bqi)
{
  int i = blockIdx.x * 256 + threadIdx.x;   // 512*1536
  if (i < NQ)
    bqi[i] = (i < DD) ? bq[i] : (i < 2 * DD) ? bk[i - DD] : (i < NC) ? bv[i - 2 * DD] : 0.f;
  if (i >= DD * NC) return;
  int n = i / NC, c = i - n * NC;
  float v = (c < DD) ? wo[n * DD + c] : opw[n * DIN + (c - DD)];
  wc[i] = f2b(v);
}

// ---------------------------------------------------------------- GEMM 64-tile: C = A @ W^T (+bias)
__global__ __launch_bounds__(256) void gemm_bt(
    const ushort* __restrict__ A, const ushort* __restrict__ W,
    const float* __restrict__ bias, float* __restrict__ outF,
    ushort* __restrict__ outB, int M, int N, int K, int act)
{
  __shared__ ushort As[64][40];
  __shared__ ushort Ws[64][40];
  int m0 = blockIdx.y * 64, n0 = blockIdx.x * 64;
  int tid = threadIdx.x, l = tid & 63, w = tid >> 6;
  int wm = (w >> 1) * 32, wn = (w & 1) * 32;
  int lr = l & 15, kl = (l >> 4) * 8;
  int srow = tid >> 2, sk = (tid & 3) * 8;
  f32x4 acc[2][2] = {};

  for (int k0 = 0; k0 < K; k0 += 32) {
    uint4 av = *(const uint4*)&A[(size_t)(m0 + srow) * K + k0 + sk];
    uint4 wv;
    if (n0 + srow < N) wv = *(const uint4*)&W[(size_t)(n0 + srow) * K + k0 + sk];
    else { wv.x = 0; wv.y = 0; wv.z = 0; wv.w = 0; }
    *(uint4*)&As[srow][sk] = av;
    *(uint4*)&Ws[srow][sk] = wv;
    __syncthreads();
    short8 a0 = *(const short8*)&As[wm + lr][kl];
    short8 a1 = *(const short8*)&As[wm + 16 + lr][kl];
    short8 b0 = *(const short8*)&Ws[wn + lr][kl];
    short8 b1 = *(const short8*)&Ws[wn + 16 + lr][kl];
    acc[0][0] = MFMA(a0, b0, acc[0][0]);
    acc[0][1] = MFMA(a0, b1, acc[0][1]);
    acc[1][0] = MFMA(a1, b0, acc[1][0]);
    acc[1][1] = MFMA(a1, b1, acc[1][1]);
    __syncthreads();
  }

  #pragma unroll
  for (int mi = 0; mi < 2; mi++)
    #pragma unroll
    for (int ni = 0; ni < 2; ni++) {
      int rbase = m0 + wm + mi * 16 + ((l >> 4) << 2);
      int col = n0 + wn + ni * 16 + lr;
      if (col < N) {
        float bval = bias ? bias[col] : 0.f;
        #pragma unroll
        for (int r = 0; r < 4; r++) {
          float v = acc[mi][ni][r] + bval;
          if (act == 1) v = (v > 20.f) ? v : log1pf(__expf(v));
          size_t o = (size_t)(rbase + r) * N + col;
          if (outF) outF[o] = v;
          if (outB) outB[o] = f2b(v);
        }
      }
    }
}

// ---------------------------------------------------------------- GEMM 128-tile (M,N mult of 128, K mult of 32)
__global__ __launch_bounds__(256) void gemm128(
    const ushort* __restrict__ A, const ushort* __restrict__ W,
    const float* __restrict__ bias, float* __restrict__ outF,
    ushort* __restrict__ outB, int M, int N, int K)
{
  __shared__ ushort As[128][40];
  __shared__ ushort Ws[128][40];
  int tid = threadIdx.x, l = tid & 63, w = tid >> 6;
  int m0 = blockIdx.y * 128, n0 = blockIdx.x * 128;
  int wm = (w >> 1) * 64, wn = (w & 1) * 64;
  int lr = l & 15, kl = (l >> 4) * 8;
  int srow = tid >> 1, sk = (tid & 1) * 16;
  f32x4 acc[4][4] = {};

  const ushort* Ap = A + (size_t)(m0 + srow) * K + sk;
  const ushort* Wp = W + (size_t)(n0 + srow) * K + sk;

  for (int k0 = 0; k0 < K; k0 += 32) {
    uint4 a0 = *(const uint4*)(Ap);
    uint4 a1 = *(const uint4*)(Ap + 8);
    uint4 b0 = *(const uint4*)(Wp);
    uint4 b1 = *(const uint4*)(Wp + 8);
    __syncthreads();
    *(uint4*)&As[srow][sk]     = a0;
    *(uint4*)&As[srow][sk + 8] = a1;
    *(uint4*)&Ws[srow][sk]     = b0;
    *(uint4*)&Ws[srow][sk + 8] = b1;
    __syncthreads();
    short8 af[4], bf[4];
    #pragma unroll
    for (int mi = 0; mi < 4; mi++) af[mi] = *(const short8*)&As[wm + mi * 16 + lr][kl];
    #pragma unroll
    for (int ni = 0; ni < 4; ni++) bf[ni] = *(const short8*)&Ws[wn + ni * 16 + lr][kl];
    #pragma unroll
    for (int mi = 0; mi < 4; mi++)
      #pragma unroll
      for (int ni = 0; ni < 4; ni++)
        acc[mi][ni] = MFMA(af[mi], bf[ni], acc[mi][ni]);
    Ap += 32; Wp += 32;
  }

  #pragma unroll
  for (int mi = 0; mi < 4; mi++)
    #pragma unroll
    for (int ni = 0; ni < 4; ni++) {
      int rbase = m0 + wm + mi * 16 + ((l >> 4) << 2);
      int col = n0 + wn + ni * 16 + lr;
      float bval = bias ? bias[col] : 0.f;
      #pragma unroll
      for (int r = 0; r < 4; r++) {
        float v = acc[mi][ni][r] + bval;
        size_t o = (size_t)(rbase + r) * N + col;
        if (outF) outF[o] = v;
        if (outB) outB[o] = f2b(v);
      }
    }
}

// ---------------------------------------------------------------- fused: flash attention (blocks 0..511, no-max softmax)  ||  x_proj GEMM (blocks 512..703)
__global__ __launch_bounds__(256) void attn_xproj(
    const ushort* __restrict__ qkv, ushort* __restrict__ comb,
    const ushort* __restrict__ ub, const ushort* __restrict__ xpw,
    float* __restrict__ dbc)
{
  __shared__ ushort smem[4 * 64 * 72];     // 36.9 KB, union for both parts
  int id = blockIdx.x;
  int tid = threadIdx.x, l = tid & 63, w = tid >> 6;

  if (id < 512) {
    // ---------------- flash attention, fixed-scale (no-max) log2 softmax ----------------
    typedef ushort row72[72];
    row72* Qs = (row72*)smem;
    row72* Ks = Qs + 64;
    row72* Vt = Ks + 64;
    row72* Ps = Vt + 64;
    int qt = 31 - (id & 31), h = (id >> 5) & 7, b = id >> 8;
    int w16 = w * 16, lr = l & 15, kl = (l >> 4) * 8;

    for (int i = tid; i < 512; i += 256) {
      int row = i >> 3, c8 = (i & 7) * 8;
      *(uint4*)&Qs[row][c8] =
          *(const uint4*)&qkv[((size_t)(b * LL + qt * 64 + row)) * NQ + h * EE + c8];
    }
    __syncthreads();

    float l_r[4] = {0.f, 0.f, 0.f, 0.f};
    f32x4 oacc[4] = {};
    const float SSC = 0.125f * LOG2E;

    for (int kv = 0; kv <= qt; kv++) {
      for (int i = tid; i < 512; i += 256) {
        int s = i >> 3, c8 = (i & 7) * 8;
        size_t rb = ((size_t)(b * LL + kv * 64 + s)) * NQ + h * EE + c8;
        *(uint4*)&Ks[s][c8] = *(const uint4*)&qkv[rb + DD];
        uint4 vv = *(const uint4*)&qkv[rb + 2 * DD];
        const ushort* pv = (const ushort*)&vv;
        #pragma unroll
        for (int jj = 0; jj < 8; jj++) Vt[c8 + jj][s] = pv[jj];
      }
      __syncthreads();

      f32x4 sacc[4] = {};
      #pragma unroll
      for (int kk = 0; kk < 2; kk++) {
        short8 aq = *(const short8*)&Qs[w16 + lr][kk * 32 + kl];
        #pragma unroll
        for (int nt = 0; nt < 4; nt++) {
          short8 bk8 = *(const short8*)&Ks[nt * 16 + lr][kk * 32 + kl];
          sacc[nt] = MFMA(aq, bk8, sacc[nt]);
        }
      }

      bool diag = (kv == qt);
      #pragma unroll
      for (int r = 0; r < 4; r++) {
        int rloc = w16 + ((l >> 4) << 2) + r;
        float rs = 0.f;
        #pragma unroll
        for (int nt = 0; nt < 4; nt++) {
          float v = sacc[nt][r] * SSC;
          if (diag && (nt * 16 + lr) > rloc) v = -1e30f;
          float p = fexp2(v);
          rs += p;
          Ps[rloc][nt * 16 + lr] = f2b(p);
        }
        rs += QP(rs, 0xB1);
        rs += QP(rs, 0x4E);
        rs += SWZ(rs, 0x101F);
        rs += SWZ(rs, 0x201F);
        l_r[r] += rs;
      }

      #pragma unroll
      for (int kk = 0; kk < 2; kk++) {
        short8 ap = *(const short8*)&Ps[w16 + lr][kk * 32 + kl];
        #pragma unroll
        for (int nt = 0; nt < 4; nt++) {
          short8 bv8 = *(const short8*)&Vt[nt * 16 + lr][kk * 32 + kl];
          oacc[nt] = MFMA(ap, bv8, oacc[nt]);
        }
      }
      __syncthreads();
    }

    #pragma unroll
    for (int nt = 0; nt < 4; nt++)
      #pragma unroll
      for (int r = 0; r < 4; r++) {
        int row = qt * 64 + w16 + ((l >> 4) << 2) + r;
        float v = oacc[nt][r] / l_r[r];
        comb[((size_t)(b * LL + row)) * NC + h * EE + nt * 16 + lr] = f2b(v);
      }
  } else {
    // ---------------- x_proj: dbc = u @ xpw^T  (M=BL, N=160, K=DIN) ----------------
    typedef ushort row40[40];
    row40* As = (row40*)smem;
    row40* Ws = As + 64;
    int rid = id - 512;                 // 192 blocks = 3 x 64
    int n0 = (rid % 3) * 64, m0 = (rid / 3) * 64;
    int wm = (w >> 1) * 32, wn = (w & 1) * 32;
    int lr = l & 15, kl = (l >> 4) * 8;
    int srow = tid >> 2, sk = (tid & 3) * 8;
    f32x4 acc[2][2] = {};

    for (int k0 = 0; k0 < DIN; k0 += 32) {
      uint4 av = *(const uint4*)&ub[(size_t)(m0 + srow) * DIN + k0 + sk];
      uint4 wv;
      if (n0 + srow < 160) wv = *(const uint4*)&xpw[(size_t)(n0 + srow) * DIN + k0 + sk];
      else { wv.x = 0; wv.y = 0; wv.z = 0; wv.w = 0; }
      *(uint4*)&As[srow][sk] = av;
      *(uint4*)&Ws[srow][sk] = wv;
      __syncthreads();
      short8 a0 = *(const short8*)&As[wm + lr][kl];
      short8 a1 = *(const short8*)&As[wm + 16 + lr][kl];
      short8 b0 = *(const short8*)&Ws[wn + lr][kl];
      short8 b1 = *(const short8*)&Ws[wn + 16 + lr][kl];
      acc[0][0] = MFMA(a0, b0, acc[0][0]);
      acc[0][1] = MFMA(a0, b1, acc[0][1]);
      acc[1][0] = MFMA(a1, b0, acc[1][0]);
      acc[1][1] = MFMA(a1, b1, acc[1][1]);
      __syncthreads();
    }

    #pragma unroll
    for (int mi = 0; mi < 2; mi++)
      #pragma unroll
      for (int ni = 0; ni < 2; ni++) {
        int rbase = m0 + wm + mi * 16 + ((l >> 4) << 2);
        int col = n0 + wn + ni * 16 + lr;
        if (col < 160) {
          #pragma unroll
          for (int r = 0; r < 4; r++)
            dbc[(size_t)(rbase + r) * 160 + col] = acc[mi][ni][r];
        }
      }
  }
}

// ---------------------------------------------------------------- depthwise causal conv (K=4) + SiLU: sliding window, 8 t per thread
__global__ __launch_bounds__(256) void conv_silu(
    const ushort* __restrict__ xz, const float* __restrict__ cw,
    const float* __restrict__ cb, ushort* __restrict__ ub)
{
  int i = blockIdx.x * 256 + threadIdx.x;        // (BL/8)*DIN threads
  int d = i & (DIN - 1);
  int r = i >> 10;
  int t0 = (r & (LL / 8 - 1)) * 8;
  int b = r >> 8;
  float c0 = cw[d * 4], c1 = cw[d * 4 + 1], c2 = cw[d * 4 + 2], c3 = cw[d * 4 + 3];
  float bias = cb[d];
  float xw[11];
  #pragma unroll
  for (int j = 0; j < 3; j++) {
    int tt = t0 - 3 + j;
    xw[j] = (tt >= 0) ? b2f(xz[((size_t)(b * LL + tt)) * NQ + XOFF + d]) : 0.f;
  }
  #pragma unroll
  for (int j = 0; j < 8; j++)
    xw[3 + j] = b2f(xz[((size_t)(b * LL + t0 + j)) * NQ + XOFF + d]);
  size_t obase = (size_t)(b * LL + t0) * DIN + d;
  #pragma unroll
  for (int j = 0; j < 8; j++) {
    float s = bias + xw[j] * c0 + xw[j + 1] * c1 + xw[j + 2] * c2 + xw[j + 3] * c3;
    ub[obase + (size_t)j * DIN] = f2b(s / (1.f + __expf(-s)));
  }
}

// ---------------------------------------------------------------- fused: dt_proj GEMM (blocks 0..1023, reads dbc f32 directly) || pack B,C (blocks 1024..1535)
__global__ __launch_bounds__(256) void dt_bc(
    const float* __restrict__ dbc, const ushort* __restrict__ dtw,
    const float* __restrict__ dtb, ushort* __restrict__ dt_b,
    unsigned* __restrict__ bbp, float4* __restrict__ bcp4)
{
  __shared__ ushort As[64][40];
  __shared__ ushort Ws[64][40];
  int id = blockIdx.x;
  int tid = threadIdx.x;
  if (id < 1024) {
    int m0 = (id >> 4) * 64, n0 = (id & 15) * 64;
    int l = tid & 63, w = tid >> 6;
    int wm = (w >> 1) * 32, wn = (w & 1) * 32;
    int lr = l & 15, kl = (l >> 4) * 8;
    int srow = tid >> 2, sk = (tid & 3) * 8;

    const float* ar = dbc + (size_t)(m0 + srow) * 160 + sk;
    short8 av;
    #pragma unroll
    for (int j = 0; j < 8; j++) ((ushort*)&av)[j] = f2b(ar[j]);
    *(short8*)&As[srow][sk] = av;
    *(uint4*)&Ws[srow][sk] = *(const uint4*)&dtw[(size_t)(n0 + srow) * RR + sk];
    __syncthreads();

    f32x4 acc[2][2] = {};
    short8 a0 = *(const short8*)&As[wm + lr][kl];
    short8 a1 = *(const short8*)&As[wm + 16 + lr][kl];
    short8 b0 = *(const short8*)&Ws[wn + lr][kl];
    short8 b1 = *(const short8*)&Ws[wn + 16 + lr][kl];
    acc[0][0] = MFMA(a0, b0, acc[0][0]);
    acc[0][1] = MFMA(a0, b1, acc[0][1]);
    acc[1][0] = MFMA(a1, b0, acc[1][0]);
    acc[1][1] = MFMA(a1, b1, acc[1][1]);

    #pragma unroll
    for (int mi = 0; mi < 2; mi++)
      #pragma unroll
      for (int ni = 0; ni < 2; ni++) {
        int rbase = m0 + wm + mi * 16 + ((l >> 4) << 2);
        int col = n0 + wn + ni * 16 + lr;
        float bval = dtb[col];
        #pragma unroll
        for (int r = 0; r < 4; r++) {
          float v = acc[mi][ni][r] + bval;
          v = (v > 20.f) ? v : log1pf(__expf(v));
          dt_b[(size_t)(rbase + r) * DIN + col] = f2b(v);
        }
      }
  } else {
    int i = (id - 1024) * 256 + tid;    // (b, tp, n): BB*1024*64
    int n = i & 63, tp = (i >> 6) & 1023, b = i >> 16;
    size_t r0 = ((size_t)(b * LL + 2 * tp)) * 160;
    float B0 = dbc[r0 + 32 + n],  C0 = dbc[r0 + 96 + n];
    float B1 = dbc[r0 + 192 + n], C1 = dbc[r0 + 256 + n];
    bbp[i] = pack_bf2(B0, B1);
    bcp4[i] = make_float4(B0, C0, B1, C1);
  }
}

// ---------------------------------------------------------------- pack dt/u/z: time-major bf16x2 arrays (bf16 sources)
__global__ __launch_bounds__(256) void pack_dtu(
    const ushort* __restrict__ dtb16, const ushort* __restrict__ ub,
    const ushort* __restrict__ xz, const float* __restrict__ dpar,
    unsigned* __restrict__ dtu_p, unsigned* __restrict__ sg_p)
{
  __shared__ float s_dt[32][65], s_du[32][65], s_gz[32][65], s_ug[32][65];
  int d0 = blockIdx.x * 64, t0 = blockIdx.y * 32;
  int tid = threadIdx.x;
  int c = tid & 63, r4 = tid >> 6;
  float Dv = dpar[d0 + c];
  #pragma unroll
  for (int k = 0; k < 8; k++) {
    int r = k * 4 + r4;
    size_t row = (size_t)(t0 + r);
    float dtv = b2f(dtb16[row * DIN + d0 + c]);
    float uv  = b2f(ub   [row * DIN + d0 + c]);
    float zz  = b2f(xz   [row * NQ + ZOFF + d0 + c]);
    float g = zz / (1.f + __expf(-zz));
    s_dt[r][c] = dtv;
    s_du[r][c] = dtv * uv;
    s_gz[r][c] = g;
    s_ug[r][c] = uv * Dv * g;
  }
  __syncthreads();
  int dl = tid >> 2, q = tid & 3;
  int b = t0 >> 11, tl0 = t0 & (LL - 1);
  size_t obase = ((size_t)(b * DIN + d0 + dl)) * LL + tl0 + q * 8;
  #pragma unroll
  for (int tt = 0; tt < 8; tt++) {
    int t = q * 8 + tt;
    dtu_p[obase + tt] = pack_bf2(s_dt[t][dl], s_du[t][dl]);
    sg_p [obase + tt] = pack_bf2(s_gz[t][dl], s_ug[t][dl]);
  }
}

// ---------------------------------------------------------------- fused chunked scan: phase1 + in-block carry + phase3
// block = (b, d), 16 waves = 16 chunks, lane = state n
__global__ __launch_bounds__(1024) void scan_fused(
    const unsigned* __restrict__ dtu_p, const unsigned* __restrict__ sg_p,
    const unsigned* __restrict__ bbp, const float4* __restrict__ bcp4,
    const float* __restrict__ alog, ushort* __restrict__ ymt)
{
  __shared__ float lds3[NCH][TC][4];      // 32 KB (phase1 uses slots 0..1)
  __shared__ float hfL[NCH][NS];          // 4 KB
  __shared__ float apL[NCH][NS];          // 4 KB
  __shared__ ushort yt[NCH][TC];          // 4 KB
  int tid = threadIdx.x, w = tid >> 6, l = tid & 63;
  int bid = blockIdx.x;
  int d = bid & (DIN - 1);
  int b = bid >> 10;
  int c = w;
  float An2 = -__expf(alog[d * NS + l]) * LOG2E;

  // ---- phase 1: suffix-sum h_final for chunk c (h0 = 0) ----
  size_t pbase = ((size_t)(b * DIN + d)) * LL + c * TC;
  unsigned p0 = dtu_p[pbase + l];
  unsigned p1 = dtu_p[pbase + 64 + l];
  float s0 = bflo(p0), s1 = bflo(p1);
  s0 = DPP_ADD(s0, 0x111, 0xf); s0 = DPP_ADD(s0, 0x112, 0xf);
  s0 = DPP_ADD(s0, 0x114, 0xf); s0 = DPP_ADD(s0, 0x118, 0xf);
  s0 = DPP_ADD(s0, 0x142, 0xa); s0 = DPP_ADD(s0, 0x143, 0xc);
  s1 = DPP_ADD(s1, 0x111, 0xf); s1 = DPP_ADD(s1, 0x112, 0xf);
  s1 = DPP_ADD(s1, 0x114, 0xf); s1 = DPP_ADD(s1, 0x118, 0xf);
  s1 = DPP_ADD(s1, 0x142, 0xa); s1 = DPP_ADD(s1, 0x143, 0xc);
  float T0 = __uint_as_float(__builtin_amdgcn_readlane(__float_as_uint(s0), 63));
  float T  = T0 + __uint_as_float(__builtin_amdgcn_readlane(__float_as_uint(s1), 63));
  lds3[w][l][0]      = T - s0;          // E_t
  lds3[w][l][1]      = bfhi(p0);        // dtu_t
  lds3[w][64 + l][0] = (T - T0) - s1;
  lds3[w][64 + l][1] = bfhi(p1);
  __syncthreads();

  {
    const unsigned* bq = bbp + ((size_t)(b * 1024 + c * 64) * 64 + l);
    float h0 = 0.f, h1 = 0.f;
    for (int g = 0; g < 16; g++) {
      unsigned bv[4];
      #pragma unroll
      for (int k = 0; k < 4; k++) bv[k] = bq[k * 64];
      const float* gb = &lds3[w][g * 8][0];
      #pragma unroll
      for (int j = 0; j < 8; j++) {
        float2 dd = *(const float2*)(gb + j * 4);
        float Bv = (j & 1) ? bfhi(bv[j >> 1]) : bflo(bv[j >> 1]);
        float a = fexp2(dd.x * An2);
        if (j & 1) h1 += a * (dd.y * Bv);
        else       h0 += a * (dd.y * Bv);
      }
      bq += 256;
    }
    hfL[w][l] = h0 + h1;
    apL[w][l] = fexp2(T * An2);
  }
  __syncthreads();

  // ---- in-block carry fold: carry for chunk c over chunks 0..c-1 ----
  float h = 0.f;
  for (int k = 0; k < c; k++) h = apL[k][l] * h + hfL[k][l];

  // ---- phase 3 LDS reload (dtu regs reused; only sg_p fetched) ----
  {
    unsigned pg0 = sg_p[pbase + l];
    unsigned pg1 = sg_p[pbase + 64 + l];
    lds3[w][l][0]      = bflo(p0);
    lds3[w][l][1]      = bfhi(p0);
    lds3[w][l][2]      = bflo(pg0);
    lds3[w][l][3]      = bfhi(pg0);
    lds3[w][64 + l][0] = bflo(p1);
    lds3[w][64 + l][1] = bfhi(p1);
    lds3[w][64 + l][2] = bflo(pg1);
    lds3[w][64 + l][3] = bfhi(pg1);
  }
  __syncthreads();

  // ---- phase 3: recurrence + batched-8 deferred reduce ----
  const float4* bq4 = bcp4 + ((size_t)(b * 1024 + c * 64) * 64 + l);
  bool s1f = l & 1, s2f = l & 2, s4f = l & 4;
  bool wl = l < 8;

  for (int g = 0; g < 16; g++) {
    float4 bcs[4];
    bcs[0] = bq4[0]; bcs[1] = bq4[64]; bcs[2] = bq4[128]; bcs[3] = bq4[192];
    const float* gb = &lds3[w][g * 8][0];
    float p[8];
    #pragma unroll
    for (int j = 0; j < 8; j++) {
      float2 dd = *(const float2*)(gb + j * 4);
      float Bv = (j & 1) ? bcs[j >> 1].z : bcs[j >> 1].x;
      float Cv = (j & 1) ? bcs[j >> 1].w : bcs[j >> 1].y;
      float a = fexp2(dd.x * An2);
      h = a * h + dd.y * Bv;
      p[j] = h * Cv;
    }
    #pragma unroll
    for (int j = 0; j < 8; j++) p[j] += QP(p[j], 0xB1);       // xor1
    float q0 = s1f ? p[1] : p[0];
    float q1 = s1f ? p[3] : p[2];
    float q2 = s1f ? p[5] : p[4];
    float q3 = s1f ? p[7] : p[6];
    q0 += QP(q0, 0x4E); q1 += QP(q1, 0x4E);                   // xor2
    q2 += QP(q2, 0x4E); q3 += QP(q3, 0x4E);
    float r0 = s2f ? q1 : q0;
    float r1 = s2f ? q3 : q2;
    r0 += SWZ(r0, 0x101F); r1 += SWZ(r1, 0x101F);             // xor4
    float s = s4f ? r1 : r0;
    s += QP(s, 0x128);                                        // xor8 (row_ror:8)
    s += SWZ(s, 0x401F);                                      // xor16
    s = xor32_add_lo(s);                                      // xor32 (permlane)

    float2 sgv = *(const float2*)(&lds3[w][g * 8 + (l & 7)][2]);
    if (wl) yt[w][g * 8 + l] = f2b(s * sgv.x + sgv.y);
    bq4 += 256;
  }
  __syncthreads();
  unsigned vv = *(const unsigned*)&yt[w][2 * l];
  ((unsigned*)(ymt + pbase))[l] = vv;
}

// ---------------------------------------------------------------- transpose ymt[b][d][t] -> comb[b][t][512 + d] (stride NC)
__global__ __launch_bounds__(256) void transpose_ym(
    const ushort* __restrict__ ymt, ushort* __restrict__ comb)
{
  __shared__ ushort tile[64][72];
  int tid = threadIdx.x;
  int bx = blockIdx.x;          // d-tile (DIN/64 = 16)
  int by = blockIdx.y;          // t-tile (LL/64 = 32)
  int b  = blockIdx.z;
  int r = tid >> 2, c16 = (tid & 3) * 16;
  const ushort* src = ymt + ((size_t)(b * DIN + bx * 64 + r)) * LL + by * 64 + c16;
  *(uint4*)&tile[r][c16]     = *(const uint4*)src;
  *(uint4*)&tile[r][c16 + 8] = *(const uint4*)(src + 8);
  __syncthreads();
  ushort tmp[16];
  #pragma unroll
  for (int j = 0; j < 16; j++) tmp[j] = tile[c16 + j][r];
  ushort* dst = comb + ((size_t)(b * LL + by * 64 + r)) * NC + DD + bx * 64 + c16;
  *(uint4*)dst       = *(uint4*)&tmp[0];
  *(uint4*)(dst + 8) = *(uint4*)&tmp[8];
}

// ---------------------------------------------------------------- residual + LayerNorm (x + combined attn+mamba)
__global__ __launch_bounds__(256) void residual_ln(
    const float* __restrict__ x, const float* __restrict__ so,
    const float* __restrict__ lw, const float* __restrict__ lb,
    float* __restrict__ out)
{
  int row = blockIdx.x * 4 + (threadIdx.x >> 6);
  int l = threadIdx.x & 63;
  size_t base = (size_t)row * DD;
  float h[8];
  float s = 0.f, s2 = 0.f;
  #pragma unroll
  for (int half = 0; half < 2; half++) {
    int c = half * 256 + l * 4;
    float4 xv = *(const float4*)(x + base + c);
    float4 sv = *(const float4*)(so + base + c);
    float* hp = h + half * 4;
    hp[0] = xv.x + sv.x;
    hp[1] = xv.y + sv.y;
    hp[2] = xv.z + sv.z;
    hp[3] = xv.w + sv.w;
    #pragma unroll
    for (int j = 0; j < 4; j++) { s += hp[j]; s2 += hp[j] * hp[j]; }
  }
  #pragma unroll
  for (int o = 1; o < 64; o <<= 1) { s += __shfl_xor(s, o); s2 += __shfl_xor(s2, o); }
  float mean = s * (1.f / DD);
  float var = s2 * (1.f / DD) - mean * mean;
  float rs = rsqrtf(var + 1e-5f);
  #pragma unroll
  for (int half = 0; half < 2; half++) {
    int c = half * 256 + l * 4;
    float4 ov;
    ov.x = (h[half*4+0] - mean) * rs * lw[c+0] + lb[c+0];
    ov.y = (h[half*4+1] - mean) * rs * lw[c+1] + lb[c+1];
    ov.z = (h[half*4+2] - mean) * rs * lw[c+2] + lb[c+2];
    ov.w = (h[half*4+3] - mean) * rs * lw[c+3] + lb[c+3];
    *(float4*)(out + base + c) = ov;
  }
}

// ---------------------------------------------------------------- host
extern "C" void kernel_launch(void* const* d_in, const int* in_sizes, int n_in,
                              void* d_out, int out_size, void* d_ws, size_t ws_size,
                              hipStream_t stream) {
  const float* x    = (const float*)d_in[0];
  const float* wq   = (const float*)d_in[1];
  const float* bq   = (const float*)d_in[2];
  const float* wk   = (const float*)d_in[3];
  const float* bk   = (const float*)d_in[4];
  const float* wv   = (const float*)d_in[5];
  const float* bv   = (const float*)d_in[6];
  const float* wo   = (const float*)d_in[7];
  const float* bo   = (const float*)d_in[8];
  const float* inw  = (const float*)d_in[9];
  const float* cw   = (const float*)d_in[10];
  const float* cb   = (const float*)d_in[11];
  const float* xpw  = (const float*)d_in[12];
  const float* dtw  = (const float*)d_in[13];
  const float* dtb  = (const float*)d_in[14];
  const float* alog = (const float*)d_in[15];
  const float* dpar = (const float*)d_in[16];
  const float* opw  = (const float*)d_in[17];
  const float* lnw  = (const float*)d_in[18];
  const float* lnb  = (const float*)d_in[19];

  char* ws = (char*)d_ws;
  size_t off = 0;
  auto alloc = [&](size_t bytes) -> void* {
    void* p = ws + off;
    off += (bytes + 255) & ~(size_t)255;
    return p;
  };

  const size_t BLD = (size_t)BL * DD;
  const size_t BLDIN = (size_t)BL * DIN;

  ushort* xf_b   = (ushort*)alloc(BLD * 2);
  ushort* wqi_b  = (ushort*)alloc((size_t)NQ * DD * 2);      // [qkv | in_proj] weights
  float*  bqi    = (float*)alloc(NQ * 4);
  ushort* xpw_b  = (ushort*)alloc(160 * DIN * 2);
  ushort* dtw_b  = (ushort*)alloc(DIN * RR * 2);
  ushort* wcomb_b= (ushort*)alloc((size_t)DD * NC * 2);
  ushort* qkvxz_b= (ushort*)alloc((size_t)BL * NQ * 2);      // 28.7 MB merged
  ushort* comb_a = (ushort*)alloc((size_t)BL * NC * 2);
  float*  sum_o  = (float*)alloc(BLD * 4);
  ushort* u_b    = (ushort*)alloc(BLDIN * 2);
  float*  dbc    = (float*)alloc((size_t)BL * 160 * 4);
  ushort* dt_b   = (ushort*)alloc(BLDIN * 2);
  ushort* ymt_b  = (ushort*)alloc(BLDIN * 2);
  unsigned* bbp  = (unsigned*)alloc((size_t)BB * (LL / 2) * NS * 4);
  float4* bcp4   = (float4*)alloc((size_t)BB * (LL / 2) * NS * sizeof(float4));
  unsigned* dtu_p = (unsigned*)alloc(BLDIN * 4);
  unsigned* sg_p  = (unsigned*)alloc(BLDIN * 4);

  // 1) convert inputs to bf16 (qkv + in_proj weights concatenated along N)
  CvtJobs cj;
  cj.src[0] = x;    cj.dst[0] = xf_b;                cj.n[0] = (int)BLD;
  cj.src[1] = wq;   cj.dst[1] = wqi_b;               cj.n[1] = DD * DD;
  cj.src[2] = wk;   cj.dst[2] = wqi_b + DD * DD;     cj.n[2] = DD * DD;
  cj.src[3] = wv;   cj.dst[3] = wqi_b + 2 * DD * DD; cj.n[3] = DD * DD;
  cj.src[4] = inw;  cj.dst[4] = wqi_b + 3 * DD * DD; cj.n[4] = 2 * DIN * DD;
  cj.src[5] = xpw;  cj.dst[5] = xpw_b;               cj.n[5] = 160 * DIN;
  cj.src[6] = dtw;  cj.dst[6] = dtw_b;               cj.n[6] = DIN * RR;
  cvt_multi<<<dim3(256, 7), 256, 0, stream>>>(cj);
  pack_wcomb<<<dim3((DD * NC + 255) / 256), 256, 0, stream>>>(wo, opw, bq, bk, bv, wcomb_b, bqi);

  // 2) merged qkv + in_proj projection (N=3584)
  gemm128<<<dim3(28, 32), 256, 0, stream>>>(xf_b, wqi_b, bqi, nullptr, qkvxz_b, BL, NQ, DD);

  // 3) depthwise conv + SiLU (sliding window, 8 t per thread)
  conv_silu<<<dim3(2048), 256, 0, stream>>>(qkvxz_b, cw, cb, u_b);

  // 4) fused: flash attention (512 blocks) || x_proj GEMM (192 blocks)
  attn_xproj<<<dim3(704), 256, 0, stream>>>(qkvxz_b, comb_a, u_b, xpw_b, dbc);

  // 5) fused: dt_proj+softplus GEMM (1024 blocks) || pack B/C (512 blocks)
  dt_bc<<<dim3(1536), 256, 0, stream>>>(dbc, dtw_b, dtb, dt_b, bbp, bcp4);

  // 6) pack time-major, then single fused scan kernel
  pack_dtu<<<dim3(16, 128), 256, 0, stream>>>(dt_b, u_b, qkvxz_b, dpar, dtu_p, sg_p);
  scan_fused<<<dim3(BB * DIN), 1024, 0, stream>>>(dtu_p, sg_p, bbp, bcp4, alog, ymt_b);
  transpose_ym<<<dim3(16, 32, BB), 256, 0, stream>>>(ymt_b, comb_a);

  // 7) combined wo-proj + out_proj via 64-tile GEMM (512 blocks, balanced)
  gemm_bt<<<dim3(8, 64), 256, 0, stream>>>(comb_a, wcomb_b, bo, sum_o, nullptr, BL, DD, NC, 0);

  // 8) residual + LayerNorm
  residual_ln<<<dim3(1024), 256, 0, stream>>>(x, sum_o, lnw, lnb, (float*)d_out);
}

// Round 15
// 346.343 us; speedup vs baseline: 1.0964x; 1.0964x over previous
//
#include <hip/hip_runtime.h>

typedef __attribute__((ext_vector_type(4))) float f32x4;
typedef __attribute__((ext_vector_type(8))) short short8;
typedef __attribute__((ext_vector_type(2))) unsigned uint2e;

#define DEV static __device__ __forceinline__

DEV ushort f2b(float f) {
  union { float f; unsigned u; } v; v.f = f;
  unsigned r = v.u + 0x7FFF + ((v.u >> 16) & 1);
  return (ushort)(r >> 16);
}
DEV unsigned pack_bf2(float lo, float hi) {
  return (unsigned)f2b(lo) | ((unsigned)f2b(hi) << 16);
}
DEV float bflo(unsigned p) { return __uint_as_float(p << 16); }
DEV float bfhi(unsigned p) { return __uint_as_float(p & 0xFFFF0000u); }
DEV float b2f(ushort u) { return __uint_as_float((unsigned)u << 16); }

// raw v_exp_f32 (2^x), no OCML denorm fixup sequence
DEV float fexp2(float x) { float r; asm("v_exp_f32 %0, %1" : "=v"(r) : "v"(x)); return r; }

// lanes 0-31 get s[lane] + s[lane+32] (hi lanes garbage — callers use lanes <8)
DEV float xor32_add_lo(float s) {
  uint2e r = __builtin_amdgcn_permlane32_swap(__float_as_uint(s), __float_as_uint(s), false, false);
  return s + __uint_as_float(r.x);
}

// DPP helpers (quad_perm / row_ror / row_bcast) and ds_swizzle xor
#define QP(x, ctrl) __int_as_float(__builtin_amdgcn_update_dpp(0, __float_as_int(x), (ctrl), 0xf, 0xf, false))
#define SWZ(x, off) __int_as_float(__builtin_amdgcn_ds_swizzle(__float_as_int(x), (off)))
#define DPP_ADD(x, ctrl, rmask) \
  ((x) + __int_as_float(__builtin_amdgcn_update_dpp(0, __float_as_int(x), (ctrl), (rmask), 0xf, false)))

#define LOG2E 1.44269504f

// ---------------------------------------------------------------- constants
#define BB    2
#define LL    2048
#define DD    512
#define HH    8
#define EE    64
#define DIN   1024
#define NS    64
#define RR    32
#define BL    4096            // B*L
#define NCH   16              // scan chunks
#define TC    128             // steps per chunk (LL/NCH)
#define NC    1536            // comb width (ctx | ym)
#define NQ    3584            // merged qkv+xz width
#define XOFF  1536            // x_in column offset in merged buffer
#define ZOFF  2560            // z column offset
#define MFMA(a,b,c) __builtin_amdgcn_mfma_f32_16x16x32_bf16((a),(b),(c),0,0,0)

// ---------------------------------------------------------------- f32 -> bf16 multi-convert
struct CvtJobs {
  const float* src[7];
  ushort*      dst[7];
  int          n[7];
};

__global__ __launch_bounds__(256) void cvt_multi(CvtJobs j) {
  int job = blockIdx.y;
  const float* s = j.src[job];
  ushort* d = j.dst[job];
  int n = j.n[job];
  for (int i = blockIdx.x * 256 + threadIdx.x; i < n; i += gridDim.x * 256)
    d[i] = f2b(s[i]);
}

// ---------------------------------------------------------------- pack combined [wo | out_proj] weight + merged bias
__global__ __launch_bounds__(256) void pack_wcomb(
    const float* __restrict__ wo, const float* __restrict__ opw,
    const float* __restrict__ bq, const float* __restrict__ bk,
    const float* __restrict__ bv, ushort* __restrict__ wc,
    float* __restrict__ bqi)
{
  int i = blockIdx.x * 256 + threadIdx.x;   // 512*1536
  if (i < NQ)
    bqi[i] = (i < DD) ? bq[i] : (i < 2 * DD) ? bk[i - DD] : (i < NC) ? bv[i - 2 * DD] : 0.f;
  if (i >= DD * NC) return;
  int n = i / NC, c = i - n * NC;
  float v = (c < DD) ? wo[n * DD + c] : opw[n * DIN + (c - DD)];
  wc[i] = f2b(v);
}

// ---------------------------------------------------------------- GEMM 64-tile: C = A @ W^T (+bias)
__global__ __launch_bounds__(256) void gemm_bt(
    const ushort* __restrict__ A, const ushort* __restrict__ W,
    const float* __restrict__ bias, float* __restrict__ outF,
    ushort* __restrict__ outB, int M, int N, int K, int act)
{
  __shared__ ushort As[64][40];
  __shared__ ushort Ws[64][40];
  int m0 = blockIdx.y * 64, n0 = blockIdx.x * 64;
  int tid = threadIdx.x, l = tid & 63, w = tid >> 6;
  int wm = (w >> 1) * 32, wn = (w & 1) * 32;
  int lr = l & 15, kl = (l >> 4) * 8;
  int srow = tid >> 2, sk = (tid & 3) * 8;
  f32x4 acc[2][2] = {};

  for (int k0 = 0; k0 < K; k0 += 32) {
    uint4 av = *(const uint4*)&A[(size_t)(m0 + srow) * K + k0 + sk];
    uint4 wv;
    if (n0 + srow < N) wv = *(const uint4*)&W[(size_t)(n0 + srow) * K + k0 + sk];
    else { wv.x = 0; wv.y = 0; wv.z = 0; wv.w = 0; }
    *(uint4*)&As[srow][sk] = av;
    *(uint4*)&Ws[srow][sk] = wv;
    __syncthreads();
    short8 a0 = *(const short8*)&As[wm + lr][kl];
    short8 a1 = *(const short8*)&As[wm + 16 + lr][kl];
    short8 b0 = *(const short8*)&Ws[wn + lr][kl];
    short8 b1 = *(const short8*)&Ws[wn + 16 + lr][kl];
    acc[0][0] = MFMA(a0, b0, acc[0][0]);
    acc[0][1] = MFMA(a0, b1, acc[0][1]);
    acc[1][0] = MFMA(a1, b0, acc[1][0]);
    acc[1][1] = MFMA(a1, b1, acc[1][1]);
    __syncthreads();
  }

  #pragma unroll
  for (int mi = 0; mi < 2; mi++)
    #pragma unroll
    for (int ni = 0; ni < 2; ni++) {
      int rbase = m0 + wm + mi * 16 + ((l >> 4) << 2);
      int col = n0 + wn + ni * 16 + lr;
      if (col < N) {
        float bval = bias ? bias[col] : 0.f;
        #pragma unroll
        for (int r = 0; r < 4; r++) {
          float v = acc[mi][ni][r] + bval;
          if (act == 1) v = (v > 20.f) ? v : log1pf(__expf(v));
          size_t o = (size_t)(rbase + r) * N + col;
          if (outF) outF[o] = v;
          if (outB) outB[o] = f2b(v);
        }
      }
    }
}

// ---------------------------------------------------------------- GEMM 128-tile (M,N mult of 128, K mult of 32)
__global__ __launch_bounds__(256) void gemm128(
    const ushort* __restrict__ A, const ushort* __restrict__ W,
    const float* __restrict__ bias, float* __restrict__ outF,
    ushort* __restrict__ outB, int M, int N, int K)
{
  __shared__ ushort As[128][40];
  __shared__ ushort Ws[128][40];
  int tid = threadIdx.x, l = tid & 63, w = tid >> 6;
  int m0 = blockIdx.y * 128, n0 = blockIdx.x * 128;
  int wm = (w >> 1) * 64, wn = (w & 1) * 64;
  int lr = l & 15, kl = (l >> 4) * 8;
  int srow = tid >> 1, sk = (tid & 1) * 16;
  f32x4 acc[4][4] = {};

  const ushort* Ap = A + (size_t)(m0 + srow) * K + sk;
  const ushort* Wp = W + (size_t)(n0 + srow) * K + sk;

  for (int k0 = 0; k0 < K; k0 += 32) {
    uint4 a0 = *(const uint4*)(Ap);
    uint4 a1 = *(const uint4*)(Ap + 8);
    uint4 b0 = *(const uint4*)(Wp);
    uint4 b1 = *(const uint4*)(Wp + 8);
    __syncthreads();
    *(uint4*)&As[srow][sk]     = a0;
    *(uint4*)&As[srow][sk + 8] = a1;
    *(uint4*)&Ws[srow][sk]     = b0;
    *(uint4*)&Ws[srow][sk + 8] = b1;
    __syncthreads();
    short8 af[4], bf[4];
    #pragma unroll
    for (int mi = 0; mi < 4; mi++) af[mi] = *(const short8*)&As[wm + mi * 16 + lr][kl];
    #pragma unroll
    for (int ni = 0; ni < 4; ni++) bf[ni] = *(const short8*)&Ws[wn + ni * 16 + lr][kl];
    #pragma unroll
    for (int mi = 0; mi < 4; mi++)
      #pragma unroll
      for (int ni = 0; ni < 4; ni++)
        acc[mi][ni] = MFMA(af[mi], bf[ni], acc[mi][ni]);
    Ap += 32; Wp += 32;
  }

  #pragma unroll
  for (int mi = 0; mi < 4; mi++)
    #pragma unroll
    for (int ni = 0; ni < 4; ni++) {
      int rbase = m0 + wm + mi * 16 + ((l >> 4) << 2);
      int col = n0 + wn + ni * 16 + lr;
      float bval = bias ? bias[col] : 0.f;
      #pragma unroll
      for (int r = 0; r < 4; r++) {
        float v = acc[mi][ni][r] + bval;
        size_t o = (size_t)(rbase + r) * N + col;
        if (outF) outF[o] = v;
        if (outB) outB[o] = f2b(v);
      }
    }
}

// ---------------------------------------------------------------- fused: flash attention (blocks 0..511, no-max softmax)  ||  x_proj GEMM (blocks 512..703)
__global__ __launch_bounds__(256) void attn_xproj(
    const ushort* __restrict__ qkv, ushort* __restrict__ comb,
    const ushort* __restrict__ ub, const ushort* __restrict__ xpw,
    float* __restrict__ dbc)
{
  __shared__ ushort smem[4 * 64 * 72];     // 36.9 KB, union for both parts
  int id = blockIdx.x;
  int tid = threadIdx.x, l = tid & 63, w = tid >> 6;

  if (id < 512) {
    // ---------------- flash attention, fixed-scale (no-max) log2 softmax ----------------
    typedef ushort row72[72];
    row72* Qs = (row72*)smem;
    row72* Ks = Qs + 64;
    row72* Vt = Ks + 64;
    row72* Ps = Vt + 64;
    int qt = 31 - (id & 31), h = (id >> 5) & 7, b = id >> 8;
    int w16 = w * 16, lr = l & 15, kl = (l >> 4) * 8;

    for (int i = tid; i < 512; i += 256) {
      int row = i >> 3, c8 = (i & 7) * 8;
      *(uint4*)&Qs[row][c8] =
          *(const uint4*)&qkv[((size_t)(b * LL + qt * 64 + row)) * NQ + h * EE + c8];
    }
    __syncthreads();

    float l_r[4] = {0.f, 0.f, 0.f, 0.f};
    f32x4 oacc[4] = {};
    const float SSC = 0.125f * LOG2E;

    for (int kv = 0; kv <= qt; kv++) {
      for (int i = tid; i < 512; i += 256) {
        int s = i >> 3, c8 = (i & 7) * 8;
        size_t rb = ((size_t)(b * LL + kv * 64 + s)) * NQ + h * EE + c8;
        *(uint4*)&Ks[s][c8] = *(const uint4*)&qkv[rb + DD];
        uint4 vv = *(const uint4*)&qkv[rb + 2 * DD];
        const ushort* pv = (const ushort*)&vv;
        #pragma unroll
        for (int jj = 0; jj < 8; jj++) Vt[c8 + jj][s] = pv[jj];
      }
      __syncthreads();

      f32x4 sacc[4] = {};
      #pragma unroll
      for (int kk = 0; kk < 2; kk++) {
        short8 aq = *(const short8*)&Qs[w16 + lr][kk * 32 + kl];
        #pragma unroll
        for (int nt = 0; nt < 4; nt++) {
          short8 bk8 = *(const short8*)&Ks[nt * 16 + lr][kk * 32 + kl];
          sacc[nt] = MFMA(aq, bk8, sacc[nt]);
        }
      }

      bool diag = (kv == qt);
      #pragma unroll
      for (int r = 0; r < 4; r++) {
        int rloc = w16 + ((l >> 4) << 2) + r;
        float rs = 0.f;
        #pragma unroll
        for (int nt = 0; nt < 4; nt++) {
          float v = sacc[nt][r] * SSC;
          if (diag && (nt * 16 + lr) > rloc) v = -1e30f;
          float p = fexp2(v);
          rs += p;
          Ps[rloc][nt * 16 + lr] = f2b(p);
        }
        rs += QP(rs, 0xB1);
        rs += QP(rs, 0x4E);
        rs += SWZ(rs, 0x101F);
        rs += SWZ(rs, 0x201F);
        l_r[r] += rs;
      }

      #pragma unroll
      for (int kk = 0; kk < 2; kk++) {
        short8 ap = *(const short8*)&Ps[w16 + lr][kk * 32 + kl];
        #pragma unroll
        for (int nt = 0; nt < 4; nt++) {
          short8 bv8 = *(const short8*)&Vt[nt * 16 + lr][kk * 32 + kl];
          oacc[nt] = MFMA(ap, bv8, oacc[nt]);
        }
      }
      __syncthreads();
    }

    #pragma unroll
    for (int nt = 0; nt < 4; nt++)
      #pragma unroll
      for (int r = 0; r < 4; r++) {
        int row = qt * 64 + w16 + ((l >> 4) << 2) + r;
        float v = oacc[nt][r] / l_r[r];
        comb[((size_t)(b * LL + row)) * NC + h * EE + nt * 16 + lr] = f2b(v);
      }
  } else {
    // ---------------- x_proj: dbc = u @ xpw^T  (M=BL, N=160, K=DIN) ----------------
    typedef ushort row40[40];
    row40* As = (row40*)smem;
    row40* Ws = As + 64;
    int rid = id - 512;                 // 192 blocks = 3 x 64
    int n0 = (rid % 3) * 64, m0 = (rid / 3) * 64;
    int wm = (w >> 1) * 32, wn = (w & 1) * 32;
    int lr = l & 15, kl = (l >> 4) * 8;
    int srow = tid >> 2, sk = (tid & 3) * 8;
    f32x4 acc[2][2] = {};

    for (int k0 = 0; k0 < DIN; k0 += 32) {
      uint4 av = *(const uint4*)&ub[(size_t)(m0 + srow) * DIN + k0 + sk];
      uint4 wv;
      if (n0 + srow < 160) wv = *(const uint4*)&xpw[(size_t)(n0 + srow) * DIN + k0 + sk];
      else { wv.x = 0; wv.y = 0; wv.z = 0; wv.w = 0; }
      *(uint4*)&As[srow][sk] = av;
      *(uint4*)&Ws[srow][sk] = wv;
      __syncthreads();
      short8 a0 = *(const short8*)&As[wm + lr][kl];
      short8 a1 = *(const short8*)&As[wm + 16 + lr][kl];
      short8 b0 = *(const short8*)&Ws[wn + lr][kl];
      short8 b1 = *(const short8*)&Ws[wn + 16 + lr][kl];
      acc[0][0] = MFMA(a0, b0, acc[0][0]);
      acc[0][1] = MFMA(a0, b1, acc[0][1]);
      acc[1][0] = MFMA(a1, b0, acc[1][0]);
      acc[1][1] = MFMA(a1, b1, acc[1][1]);
      __syncthreads();
    }

    #pragma unroll
    for (int mi = 0; mi < 2; mi++)
      #pragma unroll
      for (int ni = 0; ni < 2; ni++) {
        int rbase = m0 + wm + mi * 16 + ((l >> 4) << 2);
        int col = n0 + wn + ni * 16 + lr;
        if (col < 160) {
          #pragma unroll
          for (int r = 0; r < 4; r++)
            dbc[(size_t)(rbase + r) * 160 + col] = acc[mi][ni][r];
        }
      }
  }
}

// ---------------------------------------------------------------- depthwise causal conv (K=4) + SiLU: sliding window, 8 t per thread
__global__ __launch_bounds__(256) void conv_silu(
    const ushort* __restrict__ xz, const float* __restrict__ cw,
    const float* __restrict__ cb, ushort* __restrict__ ub)
{
  int i = blockIdx.x * 256 + threadIdx.x;        // (BL/8)*DIN threads
  int d = i & (DIN - 1);
  int r = i >> 10;
  int t0 = (r & (LL / 8 - 1)) * 8;
  int b = r >> 8;
  float c0 = cw[d * 4], c1 = cw[d * 4 + 1], c2 = cw[d * 4 + 2], c3 = cw[d * 4 + 3];
  float bias = cb[d];
  float xw[11];
  #pragma unroll
  for (int j = 0; j < 3; j++) {
    int tt = t0 - 3 + j;
    xw[j] = (tt >= 0) ? b2f(xz[((size_t)(b * LL + tt)) * NQ + XOFF + d]) : 0.f;
  }
  #pragma unroll
  for (int j = 0; j < 8; j++)
    xw[3 + j] = b2f(xz[((size_t)(b * LL + t0 + j)) * NQ + XOFF + d]);
  size_t obase = (size_t)(b * LL + t0) * DIN + d;
  #pragma unroll
  for (int j = 0; j < 8; j++) {
    float s = bias + xw[j] * c0 + xw[j + 1] * c1 + xw[j + 2] * c2 + xw[j + 3] * c3;
    ub[obase + (size_t)j * DIN] = f2b(s / (1.f + __expf(-s)));
  }
}

// ---------------------------------------------------------------- fused: dt_proj GEMM (blocks 0..1023, reads dbc f32 directly) || pack B,C (blocks 1024..1535)
__global__ __launch_bounds__(256) void dt_bc(
    const float* __restrict__ dbc, const ushort* __restrict__ dtw,
    const float* __restrict__ dtb, ushort* __restrict__ dt_b,
    unsigned* __restrict__ bbp, float4* __restrict__ bcp4)
{
  __shared__ ushort As[64][40];
  __shared__ ushort Ws[64][40];
  int id = blockIdx.x;
  int tid = threadIdx.x;
  if (id < 1024) {
    int m0 = (id >> 4) * 64, n0 = (id & 15) * 64;
    int l = tid & 63, w = tid >> 6;
    int wm = (w >> 1) * 32, wn = (w & 1) * 32;
    int lr = l & 15, kl = (l >> 4) * 8;
    int srow = tid >> 2, sk = (tid & 3) * 8;

    const float* ar = dbc + (size_t)(m0 + srow) * 160 + sk;
    short8 av;
    #pragma unroll
    for (int j = 0; j < 8; j++) ((ushort*)&av)[j] = f2b(ar[j]);
    *(short8*)&As[srow][sk] = av;
    *(uint4*)&Ws[srow][sk] = *(const uint4*)&dtw[(size_t)(n0 + srow) * RR + sk];
    __syncthreads();

    f32x4 acc[2][2] = {};
    short8 a0 = *(const short8*)&As[wm + lr][kl];
    short8 a1 = *(const short8*)&As[wm + 16 + lr][kl];
    short8 b0 = *(const short8*)&Ws[wn + lr][kl];
    short8 b1 = *(const short8*)&Ws[wn + 16 + lr][kl];
    acc[0][0] = MFMA(a0, b0, acc[0][0]);
    acc[0][1] = MFMA(a0, b1, acc[0][1]);
    acc[1][0] = MFMA(a1, b0, acc[1][0]);
    acc[1][1] = MFMA(a1, b1, acc[1][1]);

    #pragma unroll
    for (int mi = 0; mi < 2; mi++)
      #pragma unroll
      for (int ni = 0; ni < 2; ni++) {
        int rbase = m0 + wm + mi * 16 + ((l >> 4) << 2);
        int col = n0 + wn + ni * 16 + lr;
        float bval = dtb[col];
        #pragma unroll
        for (int r = 0; r < 4; r++) {
          float v = acc[mi][ni][r] + bval;
          v = (v > 20.f) ? v : log1pf(__expf(v));
          dt_b[(size_t)(rbase + r) * DIN + col] = f2b(v);
        }
      }
  } else {
    int i = (id - 1024) * 256 + tid;    // (b, tp, n): BB*1024*64
    int n = i & 63, tp = (i >> 6) & 1023, b = i >> 16;
    size_t r0 = ((size_t)(b * LL + 2 * tp)) * 160;
    float B0 = dbc[r0 + 32 + n],  C0 = dbc[r0 + 96 + n];
    float B1 = dbc[r0 + 192 + n], C1 = dbc[r0 + 256 + n];
    bbp[i] = pack_bf2(B0, B1);
    bcp4[i] = make_float4(B0, C0, B1, C1);
  }
}

// ---------------------------------------------------------------- pack dt/u/z: time-major bf16x2 arrays (bf16 sources)
__global__ __launch_bounds__(256) void pack_dtu(
    const ushort* __restrict__ dtb16, const ushort* __restrict__ ub,
    const ushort* __restrict__ xz, const float* __restrict__ dpar,
    unsigned* __restrict__ dtu_p, unsigned* __restrict__ sg_p)
{
  __shared__ float s_dt[32][65], s_du[32][65], s_gz[32][65], s_ug[32][65];
  int d0 = blockIdx.x * 64, t0 = blockIdx.y * 32;
  int tid = threadIdx.x;
  int c = tid & 63, r4 = tid >> 6;
  float Dv = dpar[d0 + c];
  #pragma unroll
  for (int k = 0; k < 8; k++) {
    int r = k * 4 + r4;
    size_t row = (size_t)(t0 + r);
    float dtv = b2f(dtb16[row * DIN + d0 + c]);
    float uv  = b2f(ub   [row * DIN + d0 + c]);
    float zz  = b2f(xz   [row * NQ + ZOFF + d0 + c]);
    float g = zz / (1.f + __expf(-zz));
    s_dt[r][c] = dtv;
    s_du[r][c] = dtv * uv;
    s_gz[r][c] = g;
    s_ug[r][c] = uv * Dv * g;
  }
  __syncthreads();
  int dl = tid >> 2, q = tid & 3;
  int b = t0 >> 11, tl0 = t0 & (LL - 1);
  size_t obase = ((size_t)(b * DIN + d0 + dl)) * LL + tl0 + q * 8;
  #pragma unroll
  for (int tt = 0; tt < 8; tt++) {
    int t = q * 8 + tt;
    dtu_p[obase + tt] = pack_bf2(s_dt[t][dl], s_du[t][dl]);
    sg_p [obase + tt] = pack_bf2(s_gz[t][dl], s_ug[t][dl]);
  }
}

// ---------------------------------------------------------------- chunked scan, phase 1 (suffix-sum form)
__global__ __launch_bounds__(256) void scan_phase1(
    const unsigned* __restrict__ dtu_p, const unsigned* __restrict__ bbp,
    const float* __restrict__ alog, float* __restrict__ hf, float* __restrict__ ap)
{
  __shared__ float lds[4][TC][2];
  int tid = threadIdx.x, w = tid >> 6, l = tid & 63;
  int wid = blockIdx.x * 4 + w;
  int d = wid & (DIN - 1);
  int c = (wid >> 10) & (NCH - 1);
  int b = wid >> 14;
  float An2 = -__expf(alog[d * NS + l]) * LOG2E;

  size_t pbase = ((size_t)(b * DIN + d)) * LL + c * TC;
  unsigned p0 = dtu_p[pbase + l];
  unsigned p1 = dtu_p[pbase + 64 + l];
  float s0 = bflo(p0), s1 = bflo(p1);
  s0 = DPP_ADD(s0, 0x111, 0xf); s0 = DPP_ADD(s0, 0x112, 0xf);
  s0 = DPP_ADD(s0, 0x114, 0xf); s0 = DPP_ADD(s0, 0x118, 0xf);
  s0 = DPP_ADD(s0, 0x142, 0xa); s0 = DPP_ADD(s0, 0x143, 0xc);
  s1 = DPP_ADD(s1, 0x111, 0xf); s1 = DPP_ADD(s1, 0x112, 0xf);
  s1 = DPP_ADD(s1, 0x114, 0xf); s1 = DPP_ADD(s1, 0x118, 0xf);
  s1 = DPP_ADD(s1, 0x142, 0xa); s1 = DPP_ADD(s1, 0x143, 0xc);
  float T0 = __uint_as_float(__builtin_amdgcn_readlane(__float_as_uint(s0), 63));
  float T  = T0 + __uint_as_float(__builtin_amdgcn_readlane(__float_as_uint(s1), 63));
  lds[w][l][0]      = T - s0;
  lds[w][l][1]      = bfhi(p0);
  lds[w][64 + l][0] = (T - T0) - s1;
  lds[w][64 + l][1] = bfhi(p1);
  __syncthreads();

  const unsigned* bq = bbp + ((size_t)(b * 1024 + c * 64) * 64 + l);
  float h0 = 0.f, h1 = 0.f;
  for (int g = 0; g < 16; g++) {
    unsigned bv[4];
    #pragma unroll
    for (int k = 0; k < 4; k++) bv[k] = bq[k * 64];
    const float* gb = &lds[w][g * 8][0];
    #pragma unroll
    for (int j = 0; j < 8; j++) {
      float2 dd = *(const float2*)(gb + j * 2);
      float Bv = (j & 1) ? bfhi(bv[j >> 1]) : bflo(bv[j >> 1]);
      float a = fexp2(dd.x * An2);
      if (j & 1) h1 += a * (dd.y * Bv);
      else       h0 += a * (dd.y * Bv);
    }
    bq += 256;
  }
  size_t o = (((size_t)((b << 10) + d) * NCH) + c) * 64 + l;
  hf[o] = h0 + h1;
  ap[o] = fexp2(T * An2);
}

// ---------------------------------------------------------------- chunked scan, phase 2 (carry combine)
__global__ __launch_bounds__(256) void scan_carry(
    const float* __restrict__ hf, const float* __restrict__ ap,
    float* __restrict__ carry)
{
  int i = blockIdx.x * 256 + threadIdx.x;   // (b, d, n)
  int n = i & 63;
  int d = (i >> 6) & (DIN - 1);
  int b = i >> 16;
  size_t base = ((size_t)((b << 10) + d) * NCH) * 64 + n;
  float cur = 0.f;
  #pragma unroll
  for (int c = 0; c < NCH; c++) {
    carry[base + (size_t)c * 64] = cur;
    cur = ap[base + (size_t)c * 64] * cur + hf[base + (size_t)c * 64];
  }
}

// ---------------------------------------------------------------- chunked scan, phase 3
__global__ __launch_bounds__(256) void scan_phase3(
    const unsigned* __restrict__ dtu_p, const unsigned* __restrict__ sg_p,
    const float4* __restrict__ bcp4, const float* __restrict__ alog,
    const float* __restrict__ carry, ushort* __restrict__ ymt)
{
  __shared__ float lds[4][TC][4];
  __shared__ ushort yt[4][TC];
  int tid = threadIdx.x, w = tid >> 6, l = tid & 63;
  int wid = blockIdx.x * 4 + w;
  int d = wid & (DIN - 1);
  int c = (wid >> 10) & (NCH - 1);
  int b = wid >> 14;
  float An2 = -__expf(alog[d * NS + l]) * LOG2E;

  size_t pbase = ((size_t)(b * DIN + d)) * LL + c * TC;
  #pragma unroll
  for (int q = 0; q < 2; q++) {
    unsigned pd = dtu_p[pbase + q * 64 + l];
    unsigned pg = sg_p [pbase + q * 64 + l];
    lds[w][q * 64 + l][0] = bflo(pd);
    lds[w][q * 64 + l][1] = bfhi(pd);
    lds[w][q * 64 + l][2] = bflo(pg);
    lds[w][q * 64 + l][3] = bfhi(pg);
  }
  __syncthreads();

  float h = carry[(((size_t)((b << 10) + d) * NCH) + c) * 64 + l];
  const float4* bq = bcp4 + ((size_t)(b * 1024 + c * 64) * 64 + l);
  bool s1f = l & 1, s2f = l & 2, s4f = l & 4;
  bool wl = l < 8;

  for (int g = 0; g < 16; g++) {
    float4 bcs[4];
    bcs[0] = bq[0]; bcs[1] = bq[64]; bcs[2] = bq[128]; bcs[3] = bq[192];
    const float* gb = &lds[w][g * 8][0];
    float p[8];
    #pragma unroll
    for (int j = 0; j < 8; j++) {
      float2 dd = *(const float2*)(gb + j * 4);
      float Bv = (j & 1) ? bcs[j >> 1].z : bcs[j >> 1].x;
      float Cv = (j & 1) ? bcs[j >> 1].w : bcs[j >> 1].y;
      float a = fexp2(dd.x * An2);
      h = a * h + dd.y * Bv;
      p[j] = h * Cv;
    }
    #pragma unroll
    for (int j = 0; j < 8; j++) p[j] += QP(p[j], 0xB1);       // xor1
    float q0 = s1f ? p[1] : p[0];
    float q1 = s1f ? p[3] : p[2];
    float q2 = s1f ? p[5] : p[4];
    float q3 = s1f ? p[7] : p[6];
    q0 += QP(q0, 0x4E); q1 += QP(q1, 0x4E);                   // xor2
    q2 += QP(q2, 0x4E); q3 += QP(q3, 0x4E);
    float r0 = s2f ? q1 : q0;
    float r1 = s2f ? q3 : q2;
    r0 += SWZ(r0, 0x101F); r1 += SWZ(r1, 0x101F);             // xor4
    float s = s4f ? r1 : r0;
    s += QP(s, 0x128);                                        // xor8 (row_ror:8)
    s += SWZ(s, 0x401F);                                      // xor16
    s = xor32_add_lo(s);                                      // xor32 (permlane)

    float2 sgv = *(const float2*)(&lds[w][g * 8 + (l & 7)][2]);
    if (wl) yt[w][g * 8 + l] = f2b(s * sgv.x + sgv.y);
    bq += 256;
  }
  __syncthreads();
  unsigned vv = *(const unsigned*)&yt[w][2 * l];
  ((unsigned*)(ymt + pbase))[l] = vv;
}

// ---------------------------------------------------------------- transpose ymt[b][d][t] -> comb[b][t][512 + d] (stride NC)
__global__ __launch_bounds__(256) void transpose_ym(
    const ushort* __restrict__ ymt, ushort* __restrict__ comb)
{
  __shared__ ushort tile[64][72];
  int tid = threadIdx.x;
  int bx = blockIdx.x;          // d-tile (DIN/64 = 16)
  int by = blockIdx.y;          // t-tile (LL/64 = 32)
  int b  = blockIdx.z;
  int r = tid >> 2, c16 = (tid & 3) * 16;
  const ushort* src = ymt + ((size_t)(b * DIN + bx * 64 + r)) * LL + by * 64 + c16;
  *(uint4*)&tile[r][c16]     = *(const uint4*)src;
  *(uint4*)&tile[r][c16 + 8] = *(const uint4*)(src + 8);
  __syncthreads();
  ushort tmp[16];
  #pragma unroll
  for (int j = 0; j < 16; j++) tmp[j] = tile[c16 + j][r];
  ushort* dst = comb + ((size_t)(b * LL + by * 64 + r)) * NC + DD + bx * 64 + c16;
  *(uint4*)dst       = *(uint4*)&tmp[0];
  *(uint4*)(dst + 8) = *(uint4*)&tmp[8];
}

// ---------------------------------------------------------------- residual + LayerNorm (x + combined attn+mamba)
__global__ __launch_bounds__(256) void residual_ln(
    const float* __restrict__ x, const float* __restrict__ so,
    const float* __restrict__ lw, const float* __restrict__ lb,
    float* __restrict__ out)
{
  int row = blockIdx.x * 4 + (threadIdx.x >> 6);
  int l = threadIdx.x & 63;
  size_t base = (size_t)row * DD;
  float h[8];
  float s = 0.f, s2 = 0.f;
  #pragma unroll
  for (int half = 0; half < 2; half++) {
    int c = half * 256 + l * 4;
    float4 xv = *(const float4*)(x + base + c);
    float4 sv = *(const float4*)(so + base + c);
    float* hp = h + half * 4;
    hp[0] = xv.x + sv.x;
    hp[1] = xv.y + sv.y;
    hp[2] = xv.z + sv.z;
    hp[3] = xv.w + sv.w;
    #pragma unroll
    for (int j = 0; j < 4; j++) { s += hp[j]; s2 += hp[j] * hp[j]; }
  }
  #pragma unroll
  for (int o = 1; o < 64; o <<= 1) { s += __shfl_xor(s, o); s2 += __shfl_xor(s2, o); }
  float mean = s * (1.f / DD);
  float var = s2 * (1.f / DD) - mean * mean;
  float rs = rsqrtf(var + 1e-5f);
  #pragma unroll
  for (int half = 0; half < 2; half++) {
    int c = half * 256 + l * 4;
    float4 ov;
    ov.x = (h[half*4+0] - mean) * rs * lw[c+0] + lb[c+0];
    ov.y = (h[half*4+1] - mean) * rs * lw[c+1] + lb[c+1];
    ov.z = (h[half*4+2] - mean) * rs * lw[c+2] + lb[c+2];
    ov.w = (h[half*4+3] - mean) * rs * lw[c+3] + lb[c+3];
    *(float4*)(out + base + c) = ov;
  }
}

// ---------------------------------------------------------------- host
extern "C" void kernel_launch(void* const* d_in, const int* in_sizes, int n_in,
                              void* d_out, int out_size, void* d_ws, size_t ws_size,
                              hipStream_t stream) {
  const float* x    = (const float*)d_in[0];
  const float* wq   = (const float*)d_in[1];
  const float* bq   = (const float*)d_in[2];
  const float* wk   = (const float*)d_in[3];
  const float* bk   = (const float*)d_in[4];
  const float* wv   = (const float*)d_in[5];
  const float* bv   = (const float*)d_in[6];
  const float* wo   = (const float*)d_in[7];
  const float* bo   = (const float*)d_in[8];
  const float* inw  = (const float*)d_in[9];
  const float* cw   = (const float*)d_in[10];
  const float* cb   = (const float*)d_in[11];
  const float* xpw  = (const float*)d_in[12];
  const float* dtw  = (const float*)d_in[13];
  const float* dtb  = (const float*)d_in[14];
  const float* alog = (const float*)d_in[15];
  const float* dpar = (const float*)d_in[16];
  const float* opw  = (const float*)d_in[17];
  const float* lnw  = (const float*)d_in[18];
  const float* lnb  = (const float*)d_in[19];

  char* ws = (char*)d_ws;
  size_t off = 0;
  auto alloc = [&](size_t bytes) -> void* {
    void* p = ws + off;
    off += (bytes + 255) & ~(size_t)255;
    return p;
  };

  const size_t BLD = (size_t)BL * DD;
  const size_t BLDIN = (size_t)BL * DIN;

  ushort* xf_b   = (ushort*)alloc(BLD * 2);
  ushort* wqi_b  = (ushort*)alloc((size_t)NQ * DD * 2);      // [qkv | in_proj] weights
  float*  bqi    = (float*)alloc(NQ * 4);
  ushort* xpw_b  = (ushort*)alloc(160 * DIN * 2);
  ushort* dtw_b  = (ushort*)alloc(DIN * RR * 2);
  ushort* wcomb_b= (ushort*)alloc((size_t)DD * NC * 2);
  ushort* qkvxz_b= (ushort*)alloc((size_t)BL * NQ * 2);      // 28.7 MB merged
  ushort* comb_a = (ushort*)alloc((size_t)BL * NC * 2);
  float*  sum_o  = (float*)alloc(BLD * 4);
  ushort* u_b    = (ushort*)alloc(BLDIN * 2);
  float*  dbc    = (float*)alloc((size_t)BL * 160 * 4);
  ushort* dt_b   = (ushort*)alloc(BLDIN * 2);
  ushort* ymt_b  = (ushort*)alloc(BLDIN * 2);
  unsigned* bbp  = (unsigned*)alloc((size_t)BB * (LL / 2) * NS * 4);
  float4* bcp4   = (float4*)alloc((size_t)BB * (LL / 2) * NS * sizeof(float4));
  unsigned* dtu_p = (unsigned*)alloc(BLDIN * 4);
  unsigned* sg_p  = (unsigned*)alloc(BLDIN * 4);

  // scan scratch: hf/ap alias qkvxz_b (dead after pack_dtu; 28.7 MB >= 16.8 MB)
  const size_t SCN = (size_t)BB * DIN * NCH * 64;
  float* hf_s    = (float*)qkvxz_b;
  float* ap_s    = hf_s + SCN;
  float* carry_s = (float*)alloc(SCN * 4);

  // 1) convert inputs to bf16 (qkv + in_proj weights concatenated along N)
  CvtJobs cj;
  cj.src[0] = x;    cj.dst[0] = xf_b;                cj.n[0] = (int)BLD;
  cj.src[1] = wq;   cj.dst[1] = wqi_b;               cj.n[1] = DD * DD;
  cj.src[2] = wk;   cj.dst[2] = wqi_b + DD * DD;     cj.n[2] = DD * DD;
  cj.src[3] = wv;   cj.dst[3] = wqi_b + 2 * DD * DD; cj.n[3] = DD * DD;
  cj.src[4] = inw;  cj.dst[4] = wqi_b + 3 * DD * DD; cj.n[4] = 2 * DIN * DD;
  cj.src[5] = xpw;  cj.dst[5] = xpw_b;               cj.n[5] = 160 * DIN;
  cj.src[6] = dtw;  cj.dst[6] = dtw_b;               cj.n[6] = DIN * RR;
  cvt_multi<<<dim3(256, 7), 256, 0, stream>>>(cj);
  pack_wcomb<<<dim3((DD * NC + 255) / 256), 256, 0, stream>>>(wo, opw, bq, bk, bv, wcomb_b, bqi);

  // 2) merged qkv + in_proj projection (N=3584)
  gemm128<<<dim3(28, 32), 256, 0, stream>>>(xf_b, wqi_b, bqi, nullptr, qkvxz_b, BL, NQ, DD);

  // 3) depthwise conv + SiLU (sliding window, 8 t per thread)
  conv_silu<<<dim3(2048), 256, 0, stream>>>(qkvxz_b, cw, cb, u_b);

  // 4) fused: flash attention (512 blocks) || x_proj GEMM (192 blocks)
  attn_xproj<<<dim3(704), 256, 0, stream>>>(qkvxz_b, comb_a, u_b, xpw_b, dbc);

  // 5) fused: dt_proj+softplus GEMM (1024 blocks) || pack B/C (512 blocks)
  dt_bc<<<dim3(1536), 256, 0, stream>>>(dbc, dtw_b, dtb, dt_b, bbp, bcp4);

  // 6) pack time-major, then chunked selective scan (3 kernels — the round-13
  //    structure; fusing them into one 1024-thread kernel REGRESSED: occupancy
  //    77%->45% and 16-wave barriers cost more than the saved carry traffic)
  pack_dtu<<<dim3(16, 128), 256, 0, stream>>>(dt_b, u_b, qkvxz_b, dpar, dtu_p, sg_p);
  scan_phase1<<<dim3(8192), 256, 0, stream>>>(dtu_p, bbp, alog, hf_s, ap_s);
  scan_carry<<<dim3(512), 256, 0, stream>>>(hf_s, ap_s, carry_s);
  scan_phase3<<<dim3(8192), 256, 0, stream>>>(dtu_p, sg_p, bcp4, alog, carry_s, ymt_b);
  transpose_ym<<<dim3(16, 32, BB), 256, 0, stream>>>(ymt_b, comb_a);

  // 7) combined wo-proj + out_proj via 64-tile GEMM (512 blocks, balanced)
  gemm_bt<<<dim3(8, 64), 256, 0, stream>>>(comb_a, wcomb_b, bo, sum_o, nullptr, BL, DD, NC, 0);

  // 8) residual + LayerNorm
  residual_ln<<<dim3(1024), 256, 0, stream>>>(x, sum_o, lnw, lnb, (float*)d_out);
}

// Round 16
// 342.271 us; speedup vs baseline: 1.1095x; 1.0119x over previous
//
#include <hip/hip_runtime.h>

typedef __attribute__((ext_vector_type(4))) float f32x4;
typedef __attribute__((ext_vector_type(8))) short short8;
typedef __attribute__((ext_vector_type(2))) unsigned uint2e;

#define DEV static __device__ __forceinline__

DEV ushort f2b(float f) {
  union { float f; unsigned u; } v; v.f = f;
  unsigned r = v.u + 0x7FFF + ((v.u >> 16) & 1);
  return (ushort)(r >> 16);
}
DEV unsigned pack_bf2(float lo, float hi) {
  return (unsigned)f2b(lo) | ((unsigned)f2b(hi) << 16);
}
DEV float bflo(unsigned p) { return __uint_as_float(p << 16); }
DEV float bfhi(unsigned p) { return __uint_as_float(p & 0xFFFF0000u); }
DEV float b2f(ushort u) { return __uint_as_float((unsigned)u << 16); }

// raw v_exp_f32 (2^x), no OCML denorm fixup sequence
DEV float fexp2(float x) { float r; asm("v_exp_f32 %0, %1" : "=v"(r) : "v"(x)); return r; }

// lanes 0-31 get s[lane] + s[lane+32] (hi lanes garbage — callers use lanes <8)
DEV float xor32_add_lo(float s) {
  uint2e r = __builtin_amdgcn_permlane32_swap(__float_as_uint(s), __float_as_uint(s), false, false);
  return s + __uint_as_float(r.x);
}

// DPP helpers (quad_perm / row_ror / row_bcast) and ds_swizzle xor
#define QP(x, ctrl) __int_as_float(__builtin_amdgcn_update_dpp(0, __float_as_int(x), (ctrl), 0xf, 0xf, false))
#define SWZ(x, off) __int_as_float(__builtin_amdgcn_ds_swizzle(__float_as_int(x), (off)))
#define DPP_ADD(x, ctrl, rmask) \
  ((x) + __int_as_float(__builtin_amdgcn_update_dpp(0, __float_as_int(x), (ctrl), (rmask), 0xf, false)))

#define LOG2E 1.44269504f

// ---------------------------------------------------------------- constants
#define BB    2
#define LL    2048
#define DD    512
#define HH    8
#define EE    64
#define DIN   1024
#define NS    64
#define RR    32
#define BL    4096            // B*L
#define NCH   16              // scan chunks
#define TC    128             // steps per chunk (LL/NCH)
#define NC    1536            // comb width (ctx | ym)
#define NQ    3584            // merged qkv+xz width
#define XOFF  1536            // x_in column offset in merged buffer
#define ZOFF  2560            // z column offset
#define MFMA(a,b,c) __builtin_amdgcn_mfma_f32_16x16x32_bf16((a),(b),(c),0,0,0)

// ---------------------------------------------------------------- f32 -> bf16 multi-convert
struct CvtJobs {
  const float* src[7];
  ushort*      dst[7];
  int          n[7];
};

__global__ __launch_bounds__(256) void cvt_multi(CvtJobs j) {
  int job = blockIdx.y;
  const float* s = j.src[job];
  ushort* d = j.dst[job];
  int n = j.n[job];
  for (int i = blockIdx.x * 256 + threadIdx.x; i < n; i += gridDim.x * 256)
    d[i] = f2b(s[i]);
}

// ---------------------------------------------------------------- pack combined [wo | out_proj] weight + merged bias
__global__ __launch_bounds__(256) void pack_wcomb(
    const float* __restrict__ wo, const float* __restrict__ opw,
    const float* __restrict__ bq, const float* __restrict__ bk,
    const float* __restrict__ bv, ushort* __restrict__ wc,
    float* __restrict__ bqi)
{
  int i = blockIdx.x * 256 + threadIdx.x;   // 512*1536
  if (i < NQ)
    bqi[i] = (i < DD) ? bq[i] : (i < 2 * DD) ? bk[i - DD] : (i < NC) ? bv[i - 2 * DD] : 0.f;
  if (i >= DD * NC) return;
  int n = i / NC, c = i - n * NC;
  float v = (c < DD) ? wo[n * DD + c] : opw[n * DIN + (c - DD)];
  wc[i] = f2b(v);
}

// ---------------------------------------------------------------- GEMM 64-tile: C = A @ W^T (+bias)
__global__ __launch_bounds__(256) void gemm_bt(
    const ushort* __restrict__ A, const ushort* __restrict__ W,
    const float* __restrict__ bias, float* __restrict__ outF,
    ushort* __restrict__ outB, int M, int N, int K, int act)
{
  __shared__ ushort As[64][40];
  __shared__ ushort Ws[64][40];
  int m0 = blockIdx.y * 64, n0 = blockIdx.x * 64;
  int tid = threadIdx.x, l = tid & 63, w = tid >> 6;
  int wm = (w >> 1) * 32, wn = (w & 1) * 32;
  int lr = l & 15, kl = (l >> 4) * 8;
  int srow = tid >> 2, sk = (tid & 3) * 8;
  f32x4 acc[2][2] = {};

  for (int k0 = 0; k0 < K; k0 += 32) {
    uint4 av = *(const uint4*)&A[(size_t)(m0 + srow) * K + k0 + sk];
    uint4 wv;
    if (n0 + srow < N) wv = *(const uint4*)&W[(size_t)(n0 + srow) * K + k0 + sk];
    else { wv.x = 0; wv.y = 0; wv.z = 0; wv.w = 0; }
    *(uint4*)&As[srow][sk] = av;
    *(uint4*)&Ws[srow][sk] = wv;
    __syncthreads();
    short8 a0 = *(const short8*)&As[wm + lr][kl];
    short8 a1 = *(const short8*)&As[wm + 16 + lr][kl];
    short8 b0 = *(const short8*)&Ws[wn + lr][kl];
    short8 b1 = *(const short8*)&Ws[wn + 16 + lr][kl];
    acc[0][0] = MFMA(a0, b0, acc[0][0]);
    acc[0][1] = MFMA(a0, b1, acc[0][1]);
    acc[1][0] = MFMA(a1, b0, acc[1][0]);
    acc[1][1] = MFMA(a1, b1, acc[1][1]);
    __syncthreads();
  }

  #pragma unroll
  for (int mi = 0; mi < 2; mi++)
    #pragma unroll
    for (int ni = 0; ni < 2; ni++) {
      int rbase = m0 + wm + mi * 16 + ((l >> 4) << 2);
      int col = n0 + wn + ni * 16 + lr;
      if (col < N) {
        float bval = bias ? bias[col] : 0.f;
        #pragma unroll
        for (int r = 0; r < 4; r++) {
          float v = acc[mi][ni][r] + bval;
          if (act == 1) v = (v > 20.f) ? v : log1pf(__expf(v));
          size_t o = (size_t)(rbase + r) * N + col;
          if (outF) outF[o] = v;
          if (outB) outB[o] = f2b(v);
        }
      }
    }
}

// ---------------------------------------------------------------- GEMM 128-tile (M,N mult of 128, K mult of 32)
__global__ __launch_bounds__(256) void gemm128(
    const ushort* __restrict__ A, const ushort* __restrict__ W,
    const float* __restrict__ bias, float* __restrict__ outF,
    ushort* __restrict__ outB, int M, int N, int K)
{
  __shared__ ushort As[128][40];
  __shared__ ushort Ws[128][40];
  int tid = threadIdx.x, l = tid & 63, w = tid >> 6;
  int m0 = blockIdx.y * 128, n0 = blockIdx.x * 128;
  int wm = (w >> 1) * 64, wn = (w & 1) * 64;
  int lr = l & 15, kl = (l >> 4) * 8;
  int srow = tid >> 1, sk = (tid & 1) * 16;
  f32x4 acc[4][4] = {};

  const ushort* Ap = A + (size_t)(m0 + srow) * K + sk;
  const ushort* Wp = W + (size_t)(n0 + srow) * K + sk;

  for (int k0 = 0; k0 < K; k0 += 32) {
    uint4 a0 = *(const uint4*)(Ap);
    uint4 a1 = *(const uint4*)(Ap + 8);
    uint4 b0 = *(const uint4*)(Wp);
    uint4 b1 = *(const uint4*)(Wp + 8);
    __syncthreads();
    *(uint4*)&As[srow][sk]     = a0;
    *(uint4*)&As[srow][sk + 8] = a1;
    *(uint4*)&Ws[srow][sk]     = b0;
    *(uint4*)&Ws[srow][sk + 8] = b1;
    __syncthreads();
    short8 af[4], bf[4];
    #pragma unroll
    for (int mi = 0; mi < 4; mi++) af[mi] = *(const short8*)&As[wm + mi * 16 + lr][kl];
    #pragma unroll
    for (int ni = 0; ni < 4; ni++) bf[ni] = *(const short8*)&Ws[wn + ni * 16 + lr][kl];
    #pragma unroll
    for (int mi = 0; mi < 4; mi++)
      #pragma unroll
      for (int ni = 0; ni < 4; ni++)
        acc[mi][ni] = MFMA(af[mi], bf[ni], acc[mi][ni]);
    Ap += 32; Wp += 32;
  }

  #pragma unroll
  for (int mi = 0; mi < 4; mi++)
    #pragma unroll
    for (int ni = 0; ni < 4; ni++) {
      int rbase = m0 + wm + mi * 16 + ((l >> 4) << 2);
      int col = n0 + wn + ni * 16 + lr;
      float bval = bias ? bias[col] : 0.f;
      #pragma unroll
      for (int r = 0; r < 4; r++) {
        float v = acc[mi][ni][r] + bval;
        size_t o = (size_t)(rbase + r) * N + col;
        if (outF) outF[o] = v;
        if (outB) outB[o] = f2b(v);
      }
    }
}

// ---------------------------------------------------------------- fused: flash attention (blocks 0..511, no-max softmax)  ||  x_proj GEMM (blocks 512..703)
__global__ __launch_bounds__(256) void attn_xproj(
    const ushort* __restrict__ qkv, ushort* __restrict__ comb,
    const ushort* __restrict__ ub, const ushort* __restrict__ xpw,
    float* __restrict__ dbc)
{
  __shared__ ushort smem[4 * 64 * 72];     // 36.9 KB, union for both parts
  int id = blockIdx.x;
  int tid = threadIdx.x, l = tid & 63, w = tid >> 6;

  if (id < 512) {
    // ---------------- flash attention, fixed-scale (no-max) log2 softmax ----------------
    typedef ushort row72[72];
    row72* Qs = (row72*)smem;
    row72* Ks = Qs + 64;
    row72* Vt = Ks + 64;
    row72* Ps = Vt + 64;
    int qt = 31 - (id & 31), h = (id >> 5) & 7, b = id >> 8;
    int w16 = w * 16, lr = l & 15, kl = (l >> 4) * 8;

    for (int i = tid; i < 512; i += 256) {
      int row = i >> 3, c8 = (i & 7) * 8;
      *(uint4*)&Qs[row][c8] =
          *(const uint4*)&qkv[((size_t)(b * LL + qt * 64 + row)) * NQ + h * EE + c8];
    }
    __syncthreads();

    float l_r[4] = {0.f, 0.f, 0.f, 0.f};
    f32x4 oacc[4] = {};
    const float SSC = 0.125f * LOG2E;

    for (int kv = 0; kv <= qt; kv++) {
      for (int i = tid; i < 512; i += 256) {
        int s = i >> 3, c8 = (i & 7) * 8;
        size_t rb = ((size_t)(b * LL + kv * 64 + s)) * NQ + h * EE + c8;
        *(uint4*)&Ks[s][c8] = *(const uint4*)&qkv[rb + DD];
        uint4 vv = *(const uint4*)&qkv[rb + 2 * DD];
        const ushort* pv = (const ushort*)&vv;
        #pragma unroll
        for (int jj = 0; jj < 8; jj++) Vt[c8 + jj][s] = pv[jj];
      }
      __syncthreads();

      f32x4 sacc[4] = {};
      #pragma unroll
      for (int kk = 0; kk < 2; kk++) {
        short8 aq = *(const short8*)&Qs[w16 + lr][kk * 32 + kl];
        #pragma unroll
        for (int nt = 0; nt < 4; nt++) {
          short8 bk8 = *(const short8*)&Ks[nt * 16 + lr][kk * 32 + kl];
          sacc[nt] = MFMA(aq, bk8, sacc[nt]);
        }
      }

      bool diag = (kv == qt);
      #pragma unroll
      for (int r = 0; r < 4; r++) {
        int rloc = w16 + ((l >> 4) << 2) + r;
        float rs = 0.f;
        #pragma unroll
        for (int nt = 0; nt < 4; nt++) {
          float v = sacc[nt][r] * SSC;
          if (diag && (nt * 16 + lr) > rloc) v = -1e30f;
          float p = fexp2(v);
          rs += p;
          Ps[rloc][nt * 16 + lr] = f2b(p);
        }
        rs += QP(rs, 0xB1);
        rs += QP(rs, 0x4E);
        rs += SWZ(rs, 0x101F);
        rs += SWZ(rs, 0x201F);
        l_r[r] += rs;
      }

      #pragma unroll
      for (int kk = 0; kk < 2; kk++) {
        short8 ap = *(const short8*)&Ps[w16 + lr][kk * 32 + kl];
        #pragma unroll
        for (int nt = 0; nt < 4; nt++) {
          short8 bv8 = *(const short8*)&Vt[nt * 16 + lr][kk * 32 + kl];
          oacc[nt] = MFMA(ap, bv8, oacc[nt]);
        }
      }
      __syncthreads();
    }

    #pragma unroll
    for (int nt = 0; nt < 4; nt++)
      #pragma unroll
      for (int r = 0; r < 4; r++) {
        int row = qt * 64 + w16 + ((l >> 4) << 2) + r;
        float v = oacc[nt][r] / l_r[r];
        comb[((size_t)(b * LL + row)) * NC + h * EE + nt * 16 + lr] = f2b(v);
      }
  } else {
    // ---------------- x_proj: dbc = u @ xpw^T  (M=BL, N=160, K=DIN) ----------------
    typedef ushort row40[40];
    row40* As = (row40*)smem;
    row40* Ws = As + 64;
    int rid = id - 512;                 // 192 blocks = 3 x 64
    int n0 = (rid % 3) * 64, m0 = (rid / 3) * 64;
    int wm = (w >> 1) * 32, wn = (w & 1) * 32;
    int lr = l & 15, kl = (l >> 4) * 8;
    int srow = tid >> 2, sk = (tid & 3) * 8;
    f32x4 acc[2][2] = {};

    for (int k0 = 0; k0 < DIN; k0 += 32) {
      uint4 av = *(const uint4*)&ub[(size_t)(m0 + srow) * DIN + k0 + sk];
      uint4 wv;
      if (n0 + srow < 160) wv = *(const uint4*)&xpw[(size_t)(n0 + srow) * DIN + k0 + sk];
      else { wv.x = 0; wv.y = 0; wv.z = 0; wv.w = 0; }
      *(uint4*)&As[srow][sk] = av;
      *(uint4*)&Ws[srow][sk] = wv;
      __syncthreads();
      short8 a0 = *(const short8*)&As[wm + lr][kl];
      short8 a1 = *(const short8*)&As[wm + 16 + lr][kl];
      short8 b0 = *(const short8*)&Ws[wn + lr][kl];
      short8 b1 = *(const short8*)&Ws[wn + 16 + lr][kl];
      acc[0][0] = MFMA(a0, b0, acc[0][0]);
      acc[0][1] = MFMA(a0, b1, acc[0][1]);
      acc[1][0] = MFMA(a1, b0, acc[1][0]);
      acc[1][1] = MFMA(a1, b1, acc[1][1]);
      __syncthreads();
    }

    #pragma unroll
    for (int mi = 0; mi < 2; mi++)
      #pragma unroll
      for (int ni = 0; ni < 2; ni++) {
        int rbase = m0 + wm + mi * 16 + ((l >> 4) << 2);
        int col = n0 + wn + ni * 16 + lr;
        if (col < 160) {
          #pragma unroll
          for (int r = 0; r < 4; r++)
            dbc[(size_t)(rbase + r) * 160 + col] = acc[mi][ni][r];
        }
      }
  }
}

// ---------------------------------------------------------------- depthwise causal conv (K=4) + SiLU: sliding window, 8 t per thread
__global__ __launch_bounds__(256) void conv_silu(
    const ushort* __restrict__ xz, const float* __restrict__ cw,
    const float* __restrict__ cb, ushort* __restrict__ ub)
{
  int i = blockIdx.x * 256 + threadIdx.x;        // (BL/8)*DIN threads
  int d = i & (DIN - 1);
  int r = i >> 10;
  int t0 = (r & (LL / 8 - 1)) * 8;
  int b = r >> 8;
  float c0 = cw[d * 4], c1 = cw[d * 4 + 1], c2 = cw[d * 4 + 2], c3 = cw[d * 4 + 3];
  float bias = cb[d];
  float xw[11];
  #pragma unroll
  for (int j = 0; j < 3; j++) {
    int tt = t0 - 3 + j;
    xw[j] = (tt >= 0) ? b2f(xz[((size_t)(b * LL + tt)) * NQ + XOFF + d]) : 0.f;
  }
  #pragma unroll
  for (int j = 0; j < 8; j++)
    xw[3 + j] = b2f(xz[((size_t)(b * LL + t0 + j)) * NQ + XOFF + d]);
  size_t obase = (size_t)(b * LL + t0) * DIN + d;
  #pragma unroll
  for (int j = 0; j < 8; j++) {
    float s = bias + xw[j] * c0 + xw[j + 1] * c1 + xw[j + 2] * c2 + xw[j + 3] * c3;
    ub[obase + (size_t)j * DIN] = f2b(s / (1.f + __expf(-s)));
  }
}

// ---------------------------------------------------------------- fused: dt_proj GEMM + time-major pack (blocks 0..1023) || pack B,C (blocks 1024..1535)
// dt-part: computes dt = softplus(dbc[:,:32] @ dtw^T + dtb) for a 64x64 (t,d)
// tile, then directly emits time-major dtu_p/sg_p (replaces pack_dtu).
__global__ __launch_bounds__(256) void dt_bc(
    const float* __restrict__ dbc, const ushort* __restrict__ dtw,
    const float* __restrict__ dtb, const float* __restrict__ dpar,
    const ushort* __restrict__ ub, const ushort* __restrict__ xz,
    unsigned* __restrict__ dtu_p, unsigned* __restrict__ sg_p,
    unsigned* __restrict__ bbp, float4* __restrict__ bcp4)
{
  __shared__ ushort As[64][40];
  __shared__ ushort Ws[64][40];
  __shared__ unsigned s_a[64][65];
  __shared__ unsigned s_b[64][65];
  int id = blockIdx.x;
  int tid = threadIdx.x;
  if (id < 1024) {
    int m0 = (id >> 4) * 64, n0 = (id & 15) * 64;
    int b = m0 >> 11, t0g = m0 & (LL - 1);
    int l = tid & 63, w = tid >> 6;
    int wm = (w >> 1) * 32, wn = (w & 1) * 32;
    int lr = l & 15, kl = (l >> 4) * 8;
    int srow = tid >> 2, sk = (tid & 3) * 8;

    const float* ar = dbc + (size_t)(m0 + srow) * 160 + sk;
    short8 av;
    #pragma unroll
    for (int j = 0; j < 8; j++) ((ushort*)&av)[j] = f2b(ar[j]);
    *(short8*)&As[srow][sk] = av;
    *(uint4*)&Ws[srow][sk] = *(const uint4*)&dtw[(size_t)(n0 + srow) * RR + sk];
    __syncthreads();

    f32x4 acc[2][2] = {};
    short8 a0 = *(const short8*)&As[wm + lr][kl];
    short8 a1 = *(const short8*)&As[wm + 16 + lr][kl];
    short8 b0 = *(const short8*)&Ws[wn + lr][kl];
    short8 b1 = *(const short8*)&Ws[wn + 16 + lr][kl];
    acc[0][0] = MFMA(a0, b0, acc[0][0]);
    acc[0][1] = MFMA(a0, b1, acc[0][1]);
    acc[1][0] = MFMA(a1, b0, acc[1][0]);
    acc[1][1] = MFMA(a1, b1, acc[1][1]);

    // softplus, stash dt (f32 bits) in LDS at [t_local][d_local]
    #pragma unroll
    for (int mi = 0; mi < 2; mi++)
      #pragma unroll
      for (int ni = 0; ni < 2; ni++) {
        int rl = wm + mi * 16 + ((l >> 4) << 2);
        int cl = wn + ni * 16 + lr;
        float bval = dtb[n0 + cl];
        #pragma unroll
        for (int r = 0; r < 4; r++) {
          float v = acc[mi][ni][r] + bval;
          v = (v > 20.f) ? v : log1pf(__expf(v));
          s_a[rl + r][cl] = __float_as_uint(v);
        }
      }
    __syncthreads();

    // build packed {dt, dt*u} and {gz, u*D*gz} in place (row-major reads)
    {
      int c = tid & 63, r4 = tid >> 6;
      float Dv = dpar[n0 + c];
      #pragma unroll
      for (int k = 0; k < 16; k++) {
        int r = k * 4 + r4;
        float dtv = __uint_as_float(s_a[r][c]);
        float uv  = b2f(ub[(size_t)(m0 + r) * DIN + n0 + c]);
        float zz  = b2f(xz[(size_t)(m0 + r) * NQ + ZOFF + n0 + c]);
        float g = zz / (1.f + __expf(-zz));
        s_a[r][c] = pack_bf2(dtv, dtv * uv);
        s_b[r][c] = pack_bf2(g, uv * Dv * g);
      }
    }
    __syncthreads();

    // transposed coalesced writes: 64 contiguous t per (d) row
    {
      int dl = tid >> 2, q = tid & 3;
      unsigned vd[16], vs[16];
      #pragma unroll
      for (int j = 0; j < 16; j++) {
        vd[j] = s_a[q * 16 + j][dl];
        vs[j] = s_b[q * 16 + j][dl];
      }
      size_t obase = ((size_t)(b * DIN + n0 + dl)) * LL + t0g + q * 16;
      #pragma unroll
      for (int jj = 0; jj < 4; jj++) {
        *(uint4*)&dtu_p[obase + jj * 4] = *(uint4*)&vd[jj * 4];
        *(uint4*)&sg_p [obase + jj * 4] = *(uint4*)&vs[jj * 4];
      }
    }
  } else {
    int i = (id - 1024) * 256 + tid;    // (b, tp, n): BB*1024*64
    int n = i & 63, tp = (i >> 6) & 1023, b = i >> 16;
    size_t r0 = ((size_t)(b * LL + 2 * tp)) * 160;
    float B0 = dbc[r0 + 32 + n],  C0 = dbc[r0 + 96 + n];
    float B1 = dbc[r0 + 192 + n], C1 = dbc[r0 + 256 + n];
    bbp[i] = pack_bf2(B0, B1);
    bcp4[i] = make_float4(B0, C0, B1, C1);
  }
}

// ---------------------------------------------------------------- fused scan phase1 + carry: block = (b,d), 4 waves x 4 chunks
__global__ __launch_bounds__(256) void scan_p1c(
    const unsigned* __restrict__ dtu_p, const unsigned* __restrict__ bbp,
    const float* __restrict__ alog, float* __restrict__ carry)
{
  __shared__ float ldsE[4][TC][2];
  __shared__ float hfL[NCH][NS];
  __shared__ float apL[NCH][NS];
  int tid = threadIdx.x, w = tid >> 6, l = tid & 63;
  int bid = blockIdx.x;
  int d = bid & (DIN - 1);
  int b = bid >> 10;
  float An2 = -__expf(alog[d * NS + l]) * LOG2E;

  for (int k = 0; k < 4; k++) {
    int cc = w * 4 + k;
    size_t pbase = ((size_t)(b * DIN + d)) * LL + cc * TC;
    unsigned p0 = dtu_p[pbase + l];
    unsigned p1 = dtu_p[pbase + 64 + l];
    float s0 = bflo(p0), s1 = bflo(p1);
    s0 = DPP_ADD(s0, 0x111, 0xf); s0 = DPP_ADD(s0, 0x112, 0xf);
    s0 = DPP_ADD(s0, 0x114, 0xf); s0 = DPP_ADD(s0, 0x118, 0xf);
    s0 = DPP_ADD(s0, 0x142, 0xa); s0 = DPP_ADD(s0, 0x143, 0xc);
    s1 = DPP_ADD(s1, 0x111, 0xf); s1 = DPP_ADD(s1, 0x112, 0xf);
    s1 = DPP_ADD(s1, 0x114, 0xf); s1 = DPP_ADD(s1, 0x118, 0xf);
    s1 = DPP_ADD(s1, 0x142, 0xa); s1 = DPP_ADD(s1, 0x143, 0xc);
    float T0 = __uint_as_float(__builtin_amdgcn_readlane(__float_as_uint(s0), 63));
    float T  = T0 + __uint_as_float(__builtin_amdgcn_readlane(__float_as_uint(s1), 63));
    ldsE[w][l][0]      = T - s0;
    ldsE[w][l][1]      = bfhi(p0);
    ldsE[w][64 + l][0] = (T - T0) - s1;
    ldsE[w][64 + l][1] = bfhi(p1);
    // wave-private LDS region: no block barrier needed

    const unsigned* bq = bbp + ((size_t)(b * 1024 + cc * 64) * 64 + l);
    float h0 = 0.f, h1 = 0.f;
    for (int g = 0; g < 16; g++) {
      unsigned bv[4];
      #pragma unroll
      for (int kk = 0; kk < 4; kk++) bv[kk] = bq[kk * 64];
      const float* gb = &ldsE[w][g * 8][0];
      #pragma unroll
      for (int j = 0; j < 8; j++) {
        float2 dd = *(const float2*)(gb + j * 2);
        float Bv = (j & 1) ? bfhi(bv[j >> 1]) : bflo(bv[j >> 1]);
        float a = fexp2(dd.x * An2);
        if (j & 1) h1 += a * (dd.y * Bv);
        else       h0 += a * (dd.y * Bv);
      }
      bq += 256;
    }
    hfL[cc][l] = h0 + h1;
    apL[cc][l] = fexp2(T * An2);
  }
  __syncthreads();

  // carry fold over all 16 chunks (each wave redundantly scans, keeps its 4)
  float cur = 0.f, myc[4];
  #pragma unroll
  for (int cc = 0; cc < NCH; cc++) {
    if ((cc >> 2) == w) myc[cc & 3] = cur;
    cur = apL[cc][l] * cur + hfL[cc][l];
  }
  size_t cbase = ((size_t)((b << 10) + d) * NCH) * 64 + l;
  #pragma unroll
  for (int k = 0; k < 4; k++)
    carry[cbase + (size_t)(w * 4 + k) * 64] = myc[k];
}

// ---------------------------------------------------------------- chunked scan, phase 3
__global__ __launch_bounds__(256) void scan_phase3(
    const unsigned* __restrict__ dtu_p, const unsigned* __restrict__ sg_p,
    const float4* __restrict__ bcp4, const float* __restrict__ alog,
    const float* __restrict__ carry, ushort* __restrict__ ymt)
{
  __shared__ float lds[4][TC][4];
  __shared__ ushort yt[4][TC];
  int tid = threadIdx.x, w = tid >> 6, l = tid & 63;
  int wid = blockIdx.x * 4 + w;
  int d = wid & (DIN - 1);
  int c = (wid >> 10) & (NCH - 1);
  int b = wid >> 14;
  float An2 = -__expf(alog[d * NS + l]) * LOG2E;

  size_t pbase = ((size_t)(b * DIN + d)) * LL + c * TC;
  #pragma unroll
  for (int q = 0; q < 2; q++) {
    unsigned pd = dtu_p[pbase + q * 64 + l];
    unsigned pg = sg_p [pbase + q * 64 + l];
    lds[w][q * 64 + l][0] = bflo(pd);
    lds[w][q * 64 + l][1] = bfhi(pd);
    lds[w][q * 64 + l][2] = bflo(pg);
    lds[w][q * 64 + l][3] = bfhi(pg);
  }
  __syncthreads();

  float h = carry[(((size_t)((b << 10) + d) * NCH) + c) * 64 + l];
  const float4* bq = bcp4 + ((size_t)(b * 1024 + c * 64) * 64 + l);
  bool s1f = l & 1, s2f = l & 2, s4f = l & 4;
  bool wl = l < 8;

  for (int g = 0; g < 16; g++) {
    float4 bcs[4];
    bcs[0] = bq[0]; bcs[1] = bq[64]; bcs[2] = bq[128]; bcs[3] = bq[192];
    const float* gb = &lds[w][g * 8][0];
    float p[8];
    #pragma unroll
    for (int j = 0; j < 8; j++) {
      float2 dd = *(const float2*)(gb + j * 4);
      float Bv = (j & 1) ? bcs[j >> 1].z : bcs[j >> 1].x;
      float Cv = (j & 1) ? bcs[j >> 1].w : bcs[j >> 1].y;
      float a = fexp2(dd.x * An2);
      h = a * h + dd.y * Bv;
      p[j] = h * Cv;
    }
    #pragma unroll
    for (int j = 0; j < 8; j++) p[j] += QP(p[j], 0xB1);       // xor1
    float q0 = s1f ? p[1] : p[0];
    float q1 = s1f ? p[3] : p[2];
    float q2 = s1f ? p[5] : p[4];
    float q3 = s1f ? p[7] : p[6];
    q0 += QP(q0, 0x4E); q1 += QP(q1, 0x4E);                   // xor2
    q2 += QP(q2, 0x4E); q3 += QP(q3, 0x4E);
    float r0 = s2f ? q1 : q0;
    float r1 = s2f ? q3 : q2;
    r0 += SWZ(r0, 0x101F); r1 += SWZ(r1, 0x101F);             // xor4
    float s = s4f ? r1 : r0;
    s += QP(s, 0x128);                                        // xor8 (row_ror:8)
    s += SWZ(s, 0x401F);                                      // xor16
    s = xor32_add_lo(s);                                      // xor32 (permlane)

    float2 sgv = *(const float2*)(&lds[w][g * 8 + (l & 7)][2]);
    if (wl) yt[w][g * 8 + l] = f2b(s * sgv.x + sgv.y);
    bq += 256;
  }
  __syncthreads();
  unsigned vv = *(const unsigned*)&yt[w][2 * l];
  ((unsigned*)(ymt + pbase))[l] = vv;
}

// ---------------------------------------------------------------- transpose ymt[b][d][t] -> comb[b][t][512 + d] (stride NC)
__global__ __launch_bounds__(256) void transpose_ym(
    const ushort* __restrict__ ymt, ushort* __restrict__ comb)
{
  __shared__ ushort tile[64][72];
  int tid = threadIdx.x;
  int bx = blockIdx.x;          // d-tile (DIN/64 = 16)
  int by = blockIdx.y;          // t-tile (LL/64 = 32)
  int b  = blockIdx.z;
  int r = tid >> 2, c16 = (tid & 3) * 16;
  const ushort* src = ymt + ((size_t)(b * DIN + bx * 64 + r)) * LL + by * 64 + c16;
  *(uint4*)&tile[r][c16]     = *(const uint4*)src;
  *(uint4*)&tile[r][c16 + 8] = *(const uint4*)(src + 8);
  __syncthreads();
  ushort tmp[16];
  #pragma unroll
  for (int j = 0; j < 16; j++) tmp[j] = tile[c16 + j][r];
  ushort* dst = comb + ((size_t)(b * LL + by * 64 + r)) * NC + DD + bx * 64 + c16;
  *(uint4*)dst       = *(uint4*)&tmp[0];
  *(uint4*)(dst + 8) = *(uint4*)&tmp[8];
}

// ---------------------------------------------------------------- residual + LayerNorm (x + combined attn+mamba)
__global__ __launch_bounds__(256) void residual_ln(
    const float* __restrict__ x, const float* __restrict__ so,
    const float* __restrict__ lw, const float* __restrict__ lb,
    float* __restrict__ out)
{
  int row = blockIdx.x * 4 + (threadIdx.x >> 6);
  int l = threadIdx.x & 63;
  size_t base = (size_t)row * DD;
  float h[8];
  float s = 0.f, s2 = 0.f;
  #pragma unroll
  for (int half = 0; half < 2; half++) {
    int c = half * 256 + l * 4;
    float4 xv = *(const float4*)(x + base + c);
    float4 sv = *(const float4*)(so + base + c);
    float* hp = h + half * 4;
    hp[0] = xv.x + sv.x;
    hp[1] = xv.y + sv.y;
    hp[2] = xv.z + sv.z;
    hp[3] = xv.w + sv.w;
    #pragma unroll
    for (int j = 0; j < 4; j++) { s += hp[j]; s2 += hp[j] * hp[j]; }
  }
  #pragma unroll
  for (int o = 1; o < 64; o <<= 1) { s += __shfl_xor(s, o); s2 += __shfl_xor(s2, o); }
  float mean = s * (1.f / DD);
  float var = s2 * (1.f / DD) - mean * mean;
  float rs = rsqrtf(var + 1e-5f);
  #pragma unroll
  for (int half = 0; half < 2; half++) {
    int c = half * 256 + l * 4;
    float4 ov;
    ov.x = (h[half*4+0] - mean) * rs * lw[c+0] + lb[c+0];
    ov.y = (h[half*4+1] - mean) * rs * lw[c+1] + lb[c+1];
    ov.z = (h[half*4+2] - mean) * rs * lw[c+2] + lb[c+2];
    ov.w = (h[half*4+3] - mean) * rs * lw[c+3] + lb[c+3];
    *(float4*)(out + base + c) = ov;
  }
}

// ---------------------------------------------------------------- host
extern "C" void kernel_launch(void* const* d_in, const int* in_sizes, int n_in,
                              void* d_out, int out_size, void* d_ws, size_t ws_size,
                              hipStream_t stream) {
  const float* x    = (const float*)d_in[0];
  const float* wq   = (const float*)d_in[1];
  const float* bq   = (const float*)d_in[2];
  const float* wk   = (const float*)d_in[3];
  const float* bk   = (const float*)d_in[4];
  const float* wv   = (const float*)d_in[5];
  const float* bv   = (const float*)d_in[6];
  const float* wo   = (const float*)d_in[7];
  const float* bo   = (const float*)d_in[8];
  const float* inw  = (const float*)d_in[9];
  const float* cw   = (const float*)d_in[10];
  const float* cb   = (const float*)d_in[11];
  const float* xpw  = (const float*)d_in[12];
  const float* dtw  = (const float*)d_in[13];
  const float* dtb  = (const float*)d_in[14];
  const float* alog = (const float*)d_in[15];
  const float* dpar = (const float*)d_in[16];
  const float* opw  = (const float*)d_in[17];
  const float* lnw  = (const float*)d_in[18];
  const float* lnb  = (const float*)d_in[19];

  char* ws = (char*)d_ws;
  size_t off = 0;
  auto alloc = [&](size_t bytes) -> void* {
    void* p = ws + off;
    off += (bytes + 255) & ~(size_t)255;
    return p;
  };

  const size_t BLD = (size_t)BL * DD;
  const size_t BLDIN = (size_t)BL * DIN;

  ushort* xf_b   = (ushort*)alloc(BLD * 2);
  ushort* wqi_b  = (ushort*)alloc((size_t)NQ * DD * 2);      // [qkv | in_proj] weights
  float*  bqi    = (float*)alloc(NQ * 4);
  ushort* xpw_b  = (ushort*)alloc(160 * DIN * 2);
  ushort* dtw_b  = (ushort*)alloc(DIN * RR * 2);
  ushort* wcomb_b= (ushort*)alloc((size_t)DD * NC * 2);
  ushort* qkvxz_b= (ushort*)alloc((size_t)BL * NQ * 2);      // 28.7 MB merged
  ushort* comb_a = (ushort*)alloc((size_t)BL * NC * 2);
  float*  sum_o  = (float*)alloc(BLD * 4);
  ushort* u_b    = (ushort*)alloc(BLDIN * 2);
  float*  dbc    = (float*)alloc((size_t)BL * 160 * 4);
  ushort* ymt_b  = (ushort*)alloc(BLDIN * 2);
  unsigned* bbp  = (unsigned*)alloc((size_t)BB * (LL / 2) * NS * 4);
  float4* bcp4   = (float4*)alloc((size_t)BB * (LL / 2) * NS * sizeof(float4));
  unsigned* dtu_p = (unsigned*)alloc(BLDIN * 4);
  unsigned* sg_p  = (unsigned*)alloc(BLDIN * 4);
  const size_t SCN = (size_t)BB * DIN * NCH * 64;
  float* carry_s = (float*)alloc(SCN * 4);

  // 1) convert inputs to bf16 (qkv + in_proj weights concatenated along N)
  CvtJobs cj;
  cj.src[0] = x;    cj.dst[0] = xf_b;                cj.n[0] = (int)BLD;
  cj.src[1] = wq;   cj.dst[1] = wqi_b;               cj.n[1] = DD * DD;
  cj.src[2] = wk;   cj.dst[2] = wqi_b + DD * DD;     cj.n[2] = DD * DD;
  cj.src[3] = wv;   cj.dst[3] = wqi_b + 2 * DD * DD; cj.n[3] = DD * DD;
  cj.src[4] = inw;  cj.dst[4] = wqi_b + 3 * DD * DD; cj.n[4] = 2 * DIN * DD;
  cj.src[5] = xpw;  cj.dst[5] = xpw_b;               cj.n[5] = 160 * DIN;
  cj.src[6] = dtw;  cj.dst[6] = dtw_b;               cj.n[6] = DIN * RR;
  cvt_multi<<<dim3(256, 7), 256, 0, stream>>>(cj);
  pack_wcomb<<<dim3((DD * NC + 255) / 256), 256, 0, stream>>>(wo, opw, bq, bk, bv, wcomb_b, bqi);

  // 2) merged qkv + in_proj projection (N=3584)
  gemm128<<<dim3(28, 32), 256, 0, stream>>>(xf_b, wqi_b, bqi, nullptr, qkvxz_b, BL, NQ, DD);

  // 3) depthwise conv + SiLU (sliding window, 8 t per thread)
  conv_silu<<<dim3(2048), 256, 0, stream>>>(qkvxz_b, cw, cb, u_b);

  // 4) fused: flash attention (512 blocks) || x_proj GEMM (192 blocks)
  attn_xproj<<<dim3(704), 256, 0, stream>>>(qkvxz_b, comb_a, u_b, xpw_b, dbc);

  // 5) fused: dt_proj+softplus+time-major pack (1024 blocks) || pack B/C (512 blocks)
  dt_bc<<<dim3(1536), 256, 0, stream>>>(dbc, dtw_b, dtb, dpar, u_b, qkvxz_b,
                                        dtu_p, sg_p, bbp, bcp4);

  // 6) chunked selective scan: [phase1+carry fused] then phase3
  scan_p1c<<<dim3(BB * DIN), 256, 0, stream>>>(dtu_p, bbp, alog, carry_s);
  scan_phase3<<<dim3(8192), 256, 0, stream>>>(dtu_p, sg_p, bcp4, alog, carry_s, ymt_b);
  transpose_ym<<<dim3(16, 32, BB), 256, 0, stream>>>(ymt_b, comb_a);

  // 7) combined wo-proj + out_proj via 64-tile GEMM (512 blocks, balanced)
  gemm_bt<<<dim3(8, 64), 256, 0, stream>>>(comb_a, wcomb_b, bo, sum_o, nullptr, BL, DD, NC, 0);

  // 8) residual + LayerNorm
  residual_ln<<<dim3(1024), 256, 0, stream>>>(x, sum_o, lnw, lnb, (float*)d_out);
}

// Round 17
// 338.222 us; speedup vs baseline: 1.1227x; 1.0120x over previous
//
#include <hip/hip_runtime.h>

typedef __attribute__((ext_vector_type(4))) float f32x4;
typedef __attribute__((ext_vector_type(8))) short short8;
typedef __attribute__((ext_vector_type(2))) unsigned uint2e;

#define DEV static __device__ __forceinline__

DEV ushort f2b(float f) {
  union { float f; unsigned u; } v; v.f = f;
  unsigned r = v.u + 0x7FFF + ((v.u >> 16) & 1);
  return (ushort)(r >> 16);
}
DEV unsigned pack_bf2(float lo, float hi) {
  return (unsigned)f2b(lo) | ((unsigned)f2b(hi) << 16);
}
DEV float bflo(unsigned p) { return __uint_as_float(p << 16); }
DEV float bfhi(unsigned p) { return __uint_as_float(p & 0xFFFF0000u); }
DEV float b2f(ushort u) { return __uint_as_float((unsigned)u << 16); }

// raw v_exp_f32 (2^x), no OCML denorm fixup sequence
DEV float fexp2(float x) { float r; asm("v_exp_f32 %0, %1" : "=v"(r) : "v"(x)); return r; }

// lanes 0-31 get s[lane] + s[lane+32] (hi lanes garbage — callers use lanes <8)
DEV float xor32_add_lo(float s) {
  uint2e r = __builtin_amdgcn_permlane32_swap(__float_as_uint(s), __float_as_uint(s), false, false);
  return s + __uint_as_float(r.x);
}

// async global->LDS, 16B per lane; LDS dest = wave-uniform base + lane*16
DEV void gl_lds16(const ushort* g, ushort* l) {
  __builtin_amdgcn_global_load_lds(
      (const __attribute__((address_space(1))) unsigned int*)g,
      (__attribute__((address_space(3))) unsigned int*)l, 16, 0, 0);
}

// DPP helpers (quad_perm / row_ror / row_bcast) and ds_swizzle xor
#define QP(x, ctrl) __int_as_float(__builtin_amdgcn_update_dpp(0, __float_as_int(x), (ctrl), 0xf, 0xf, false))
#define SWZ(x, off) __int_as_float(__builtin_amdgcn_ds_swizzle(__float_as_int(x), (off)))
#define DPP_ADD(x, ctrl, rmask) \
  ((x) + __int_as_float(__builtin_amdgcn_update_dpp(0, __float_as_int(x), (ctrl), (rmask), 0xf, false)))

#define LOG2E 1.44269504f

// ---------------------------------------------------------------- constants
#define BB    2
#define LL    2048
#define DD    512
#define HH    8
#define EE    64
#define DIN   1024
#define NS    64
#define RR    32
#define BL    4096            // B*L
#define NCH   16              // scan chunks
#define TC    128             // steps per chunk (LL/NCH)
#define NC    1536            // comb width (ctx | ym)
#define NQ    3584            // merged qkv+xz width
#define XOFF  1536            // x_in column offset in merged buffer
#define ZOFF  2560            // z column offset
#define MFMA(a,b,c) __builtin_amdgcn_mfma_f32_16x16x32_bf16((a),(b),(c),0,0,0)

// ---------------------------------------------------------------- f32 -> bf16 multi-convert
struct CvtJobs {
  const float* src[7];
  ushort*      dst[7];
  int          n[7];
};

__global__ __launch_bounds__(256) void cvt_multi(CvtJobs j) {
  int job = blockIdx.y;
  const float* s = j.src[job];
  ushort* d = j.dst[job];
  int n = j.n[job];
  for (int i = blockIdx.x * 256 + threadIdx.x; i < n; i += gridDim.x * 256)
    d[i] = f2b(s[i]);
}

// ---------------------------------------------------------------- pack combined [wo | out_proj] weight + merged bias
__global__ __launch_bounds__(256) void pack_wcomb(
    const float* __restrict__ wo, const float* __restrict__ opw,
    const float* __restrict__ bq, const float* __restrict__ bk,
    const float* __restrict__ bv, ushort* __restrict__ wc,
    float* __restrict__ bqi)
{
  int i = blockIdx.x * 256 + threadIdx.x;   // 512*1536
  if (i < NQ)
    bqi[i] = (i < DD) ? bq[i] : (i < 2 * DD) ? bk[i - DD] : (i < NC) ? bv[i - 2 * DD] : 0.f;
  if (i >= DD * NC) return;
  int n = i / NC, c = i - n * NC;
  float v = (c < DD) ? wo[n * DD + c] : opw[n * DIN + (c - DD)];
  wc[i] = f2b(v);
}

// ---------------------------------------------------------------- GEMM 64-tile, global_load_lds staging (full tiles only)
__global__ __launch_bounds__(256) void gemm_bt(
    const ushort* __restrict__ A, const ushort* __restrict__ W,
    const float* __restrict__ bias, float* __restrict__ outF,
    ushort* __restrict__ outB, int M, int N, int K, int act)
{
  __shared__ ushort As[64 * 32];
  __shared__ ushort Ws[64 * 32];
  int m0 = blockIdx.y * 64, n0 = blockIdx.x * 64;
  int tid = threadIdx.x, l = tid & 63, w = tid >> 6;
  int wm = (w >> 1) * 32, wn = (w & 1) * 32;
  int lr = l & 15, kl = (l >> 4) * 8;
  int srow = w * 16 + (l >> 2), scol = (l & 3) * 8;
  const ushort* gA = A + (size_t)(m0 + srow) * K + scol;
  const ushort* gW = W + (size_t)(n0 + srow) * K + scol;
  ushort* lA = As + w * 512;
  ushort* lW = Ws + w * 512;
  f32x4 acc[2][2] = {};

  for (int k0 = 0; k0 < K; k0 += 32) {
    __syncthreads();
    gl_lds16(gA, lA);
    gl_lds16(gW, lW);
    __syncthreads();
    short8 a0 = *(const short8*)&As[(wm + lr) * 32 + kl];
    short8 a1 = *(const short8*)&As[(wm + 16 + lr) * 32 + kl];
    short8 b0 = *(const short8*)&Ws[(wn + lr) * 32 + kl];
    short8 b1 = *(const short8*)&Ws[(wn + 16 + lr) * 32 + kl];
    acc[0][0] = MFMA(a0, b0, acc[0][0]);
    acc[0][1] = MFMA(a0, b1, acc[0][1]);
    acc[1][0] = MFMA(a1, b0, acc[1][0]);
    acc[1][1] = MFMA(a1, b1, acc[1][1]);
    gA += 32; gW += 32;
  }

  #pragma unroll
  for (int mi = 0; mi < 2; mi++)
    #pragma unroll
    for (int ni = 0; ni < 2; ni++) {
      int rbase = m0 + wm + mi * 16 + ((l >> 4) << 2);
      int col = n0 + wn + ni * 16 + lr;
      float bval = bias ? bias[col] : 0.f;
      #pragma unroll
      for (int r = 0; r < 4; r++) {
        float v = acc[mi][ni][r] + bval;
        if (act == 1) v = (v > 20.f) ? v : log1pf(__expf(v));
        size_t o = (size_t)(rbase + r) * N + col;
        if (outF) outF[o] = v;
        if (outB) outB[o] = f2b(v);
      }
    }
}

// ---------------------------------------------------------------- GEMM 128-tile, global_load_lds staging (M,N mult of 128, K mult of 32)
__global__ __launch_bounds__(256) void gemm128(
    const ushort* __restrict__ A, const ushort* __restrict__ W,
    const float* __restrict__ bias, float* __restrict__ outF,
    ushort* __restrict__ outB, int M, int N, int K)
{
  __shared__ ushort As[128 * 32];
  __shared__ ushort Ws[128 * 32];
  int tid = threadIdx.x, l = tid & 63, w = tid >> 6;
  int m0 = blockIdx.y * 128, n0 = blockIdx.x * 128;
  int wm = (w >> 1) * 64, wn = (w & 1) * 64;
  int lr = l & 15, kl = (l >> 4) * 8;
  f32x4 acc[4][4] = {};

  // staging: issue i of wave w covers LDS bytes (w*2+i)*1024..+1024
  // lane l -> LDS byte base + l*16 -> row (w*2+i)*16 + (l>>2), col ushort (l&3)*8
  int srow = w * 32 + (l >> 2), scol = (l & 3) * 8;
  const ushort* gA0 = A + (size_t)(m0 + srow) * K + scol;
  const ushort* gA1 = gA0 + (size_t)16 * K;
  const ushort* gW0 = W + (size_t)(n0 + srow) * K + scol;
  const ushort* gW1 = gW0 + (size_t)16 * K;
  ushort* lA0 = As + w * 1024;
  ushort* lA1 = As + w * 1024 + 512;
  ushort* lW0 = Ws + w * 1024;
  ushort* lW1 = Ws + w * 1024 + 512;

  for (int k0 = 0; k0 < K; k0 += 32) {
    __syncthreads();
    gl_lds16(gA0, lA0);
    gl_lds16(gA1, lA1);
    gl_lds16(gW0, lW0);
    gl_lds16(gW1, lW1);
    __syncthreads();
    short8 af[4], bf[4];
    #pragma unroll
    for (int mi = 0; mi < 4; mi++) af[mi] = *(const short8*)&As[(wm + mi * 16 + lr) * 32 + kl];
    #pragma unroll
    for (int ni = 0; ni < 4; ni++) bf[ni] = *(const short8*)&Ws[(wn + ni * 16 + lr) * 32 + kl];
    #pragma unroll
    for (int mi = 0; mi < 4; mi++)
      #pragma unroll
      for (int ni = 0; ni < 4; ni++)
        acc[mi][ni] = MFMA(af[mi], bf[ni], acc[mi][ni]);
    gA0 += 32; gA1 += 32; gW0 += 32; gW1 += 32;
  }

  #pragma unroll
  for (int mi = 0; mi < 4; mi++)
    #pragma unroll
    for (int ni = 0; ni < 4; ni++) {
      int rbase = m0 + wm + mi * 16 + ((l >> 4) << 2);
      int col = n0 + wn + ni * 16 + lr;
      float bval = bias ? bias[col] : 0.f;
      #pragma unroll
      for (int r = 0; r < 4; r++) {
        float v = acc[mi][ni][r] + bval;
        size_t o = (size_t)(rbase + r) * N + col;
        if (outF) outF[o] = v;
        if (outB) outB[o] = f2b(v);
      }
    }
}

// ---------------------------------------------------------------- fused: flash attention (blocks 0..511, no-max softmax)  ||  x_proj GEMM (blocks 512..703)
__global__ __launch_bounds__(256) void attn_xproj(
    const ushort* __restrict__ qkv, ushort* __restrict__ comb,
    const ushort* __restrict__ ub, const ushort* __restrict__ xpw,
    float* __restrict__ dbc)
{
  __shared__ ushort smem[4 * 64 * 72];     // 36.9 KB, union for both parts
  int id = blockIdx.x;
  int tid = threadIdx.x, l = tid & 63, w = tid >> 6;

  if (id < 512) {
    // ---------------- flash attention, fixed-scale (no-max) log2 softmax ----------------
    typedef ushort row72[72];
    row72* Qs = (row72*)smem;
    row72* Ks = Qs + 64;
    row72* Vt = Ks + 64;
    row72* Ps = Vt + 64;
    int qt = 31 - (id & 31), h = (id >> 5) & 7, b = id >> 8;
    int w16 = w * 16, lr = l & 15, kl = (l >> 4) * 8;

    for (int i = tid; i < 512; i += 256) {
      int row = i >> 3, c8 = (i & 7) * 8;
      *(uint4*)&Qs[row][c8] =
          *(const uint4*)&qkv[((size_t)(b * LL + qt * 64 + row)) * NQ + h * EE + c8];
    }
    __syncthreads();

    float l_r[4] = {0.f, 0.f, 0.f, 0.f};
    f32x4 oacc[4] = {};
    const float SSC = 0.125f * LOG2E;

    for (int kv = 0; kv <= qt; kv++) {
      for (int i = tid; i < 512; i += 256) {
        int s = i >> 3, c8 = (i & 7) * 8;
        size_t rb = ((size_t)(b * LL + kv * 64 + s)) * NQ + h * EE + c8;
        *(uint4*)&Ks[s][c8] = *(const uint4*)&qkv[rb + DD];
        uint4 vv = *(const uint4*)&qkv[rb + 2 * DD];
        const ushort* pv = (const ushort*)&vv;
        #pragma unroll
        for (int jj = 0; jj < 8; jj++) Vt[c8 + jj][s] = pv[jj];
      }
      __syncthreads();

      f32x4 sacc[4] = {};
      #pragma unroll
      for (int kk = 0; kk < 2; kk++) {
        short8 aq = *(const short8*)&Qs[w16 + lr][kk * 32 + kl];
        #pragma unroll
        for (int nt = 0; nt < 4; nt++) {
          short8 bk8 = *(const short8*)&Ks[nt * 16 + lr][kk * 32 + kl];
          sacc[nt] = MFMA(aq, bk8, sacc[nt]);
        }
      }

      bool diag = (kv == qt);
      #pragma unroll
      for (int r = 0; r < 4; r++) {
        int rloc = w16 + ((l >> 4) << 2) + r;
        float rs = 0.f;
        #pragma unroll
        for (int nt = 0; nt < 4; nt++) {
          float v = sacc[nt][r] * SSC;
          if (diag && (nt * 16 + lr) > rloc) v = -1e30f;
          float p = fexp2(v);
          rs += p;
          Ps[rloc][nt * 16 + lr] = f2b(p);
        }
        rs += QP(rs, 0xB1);
        rs += QP(rs, 0x4E);
        rs += SWZ(rs, 0x101F);
        rs += SWZ(rs, 0x201F);
        l_r[r] += rs;
      }

      #pragma unroll
      for (int kk = 0; kk < 2; kk++) {
        short8 ap = *(const short8*)&Ps[w16 + lr][kk * 32 + kl];
        #pragma unroll
        for (int nt = 0; nt < 4; nt++) {
          short8 bv8 = *(const short8*)&Vt[nt * 16 + lr][kk * 32 + kl];
          oacc[nt] = MFMA(ap, bv8, oacc[nt]);
        }
      }
      __syncthreads();
    }

    #pragma unroll
    for (int nt = 0; nt < 4; nt++)
      #pragma unroll
      for (int r = 0; r < 4; r++) {
        int row = qt * 64 + w16 + ((l >> 4) << 2) + r;
        float v = oacc[nt][r] / l_r[r];
        comb[((size_t)(b * LL + row)) * NC + h * EE + nt * 16 + lr] = f2b(v);
      }
  } else {
    // ---------------- x_proj: dbc = u @ xpw^T  (M=BL, N=160, K=DIN) ----------------
    typedef ushort row40[40];
    row40* As = (row40*)smem;
    row40* Ws = As + 64;
    int rid = id - 512;                 // 192 blocks = 3 x 64
    int n0 = (rid % 3) * 64, m0 = (rid / 3) * 64;
    int wm = (w >> 1) * 32, wn = (w & 1) * 32;
    int lr = l & 15, kl = (l >> 4) * 8;
    int srow = tid >> 2, sk = (tid & 3) * 8;
    f32x4 acc[2][2] = {};

    for (int k0 = 0; k0 < DIN; k0 += 32) {
      uint4 av = *(const uint4*)&ub[(size_t)(m0 + srow) * DIN + k0 + sk];
      uint4 wv;
      if (n0 + srow < 160) wv = *(const uint4*)&xpw[(size_t)(n0 + srow) * DIN + k0 + sk];
      else { wv.x = 0; wv.y = 0; wv.z = 0; wv.w = 0; }
      *(uint4*)&As[srow][sk] = av;
      *(uint4*)&Ws[srow][sk] = wv;
      __syncthreads();
      short8 a0 = *(const short8*)&As[wm + lr][kl];
      short8 a1 = *(const short8*)&As[wm + 16 + lr][kl];
      short8 b0 = *(const short8*)&Ws[wn + lr][kl];
      short8 b1 = *(const short8*)&Ws[wn + 16 + lr][kl];
      acc[0][0] = MFMA(a0, b0, acc[0][0]);
      acc[0][1] = MFMA(a0, b1, acc[0][1]);
      acc[1][0] = MFMA(a1, b0, acc[1][0]);
      acc[1][1] = MFMA(a1, b1, acc[1][1]);
      __syncthreads();
    }

    #pragma unroll
    for (int mi = 0; mi < 2; mi++)
      #pragma unroll
      for (int ni = 0; ni < 2; ni++) {
        int rbase = m0 + wm + mi * 16 + ((l >> 4) << 2);
        int col = n0 + wn + ni * 16 + lr;
        if (col < 160) {
          #pragma unroll
          for (int r = 0; r < 4; r++)
            dbc[(size_t)(rbase + r) * 160 + col] = acc[mi][ni][r];
        }
      }
  }
}

// ---------------------------------------------------------------- depthwise causal conv (K=4) + SiLU: sliding window, 8 t per thread
__global__ __launch_bounds__(256) void conv_silu(
    const ushort* __restrict__ xz, const float* __restrict__ cw,
    const float* __restrict__ cb, ushort* __restrict__ ub)
{
  int i = blockIdx.x * 256 + threadIdx.x;        // (BL/8)*DIN threads
  int d = i & (DIN - 1);
  int r = i >> 10;
  int t0 = (r & (LL / 8 - 1)) * 8;
  int b = r >> 8;
  float c0 = cw[d * 4], c1 = cw[d * 4 + 1], c2 = cw[d * 4 + 2], c3 = cw[d * 4 + 3];
  float bias = cb[d];
  float xw[11];
  #pragma unroll
  for (int j = 0; j < 3; j++) {
    int tt = t0 - 3 + j;
    xw[j] = (tt >= 0) ? b2f(xz[((size_t)(b * LL + tt)) * NQ + XOFF + d]) : 0.f;
  }
  #pragma unroll
  for (int j = 0; j < 8; j++)
    xw[3 + j] = b2f(xz[((size_t)(b * LL + t0 + j)) * NQ + XOFF + d]);
  size_t obase = (size_t)(b * LL + t0) * DIN + d;
  #pragma unroll
  for (int j = 0; j < 8; j++) {
    float s = bias + xw[j] * c0 + xw[j + 1] * c1 + xw[j + 2] * c2 + xw[j + 3] * c3;
    ub[obase + (size_t)j * DIN] = f2b(s / (1.f + __expf(-s)));
  }
}

// ---------------------------------------------------------------- fused: dt_proj GEMM + time-major pack (blocks 0..1023) || pack B,C (blocks 1024..1535)
__global__ __launch_bounds__(256) void dt_bc(
    const float* __restrict__ dbc, const ushort* __restrict__ dtw,
    const float* __restrict__ dtb, const float* __restrict__ dpar,
    const ushort* __restrict__ ub, const ushort* __restrict__ xz,
    unsigned* __restrict__ dtu_p, unsigned* __restrict__ sg_p,
    unsigned* __restrict__ bbp, float4* __restrict__ bcp4)
{
  __shared__ ushort As[64][40];
  __shared__ ushort Ws[64][40];
  __shared__ unsigned s_a[64][65];
  __shared__ unsigned s_b[64][65];
  int id = blockIdx.x;
  int tid = threadIdx.x;
  if (id < 1024) {
    int m0 = (id >> 4) * 64, n0 = (id & 15) * 64;
    int b = m0 >> 11, t0g = m0 & (LL - 1);
    int l = tid & 63, w = tid >> 6;
    int wm = (w >> 1) * 32, wn = (w & 1) * 32;
    int lr = l & 15, kl = (l >> 4) * 8;
    int srow = tid >> 2, sk = (tid & 3) * 8;

    const float* ar = dbc + (size_t)(m0 + srow) * 160 + sk;
    short8 av;
    #pragma unroll
    for (int j = 0; j < 8; j++) ((ushort*)&av)[j] = f2b(ar[j]);
    *(short8*)&As[srow][sk] = av;
    *(uint4*)&Ws[srow][sk] = *(const uint4*)&dtw[(size_t)(n0 + srow) * RR + sk];
    __syncthreads();

    f32x4 acc[2][2] = {};
    short8 a0 = *(const short8*)&As[wm + lr][kl];
    short8 a1 = *(const short8*)&As[wm + 16 + lr][kl];
    short8 b0 = *(const short8*)&Ws[wn + lr][kl];
    short8 b1 = *(const short8*)&Ws[wn + 16 + lr][kl];
    acc[0][0] = MFMA(a0, b0, acc[0][0]);
    acc[0][1] = MFMA(a0, b1, acc[0][1]);
    acc[1][0] = MFMA(a1, b0, acc[1][0]);
    acc[1][1] = MFMA(a1, b1, acc[1][1]);

    // softplus, stash dt (f32 bits) in LDS at [t_local][d_local]
    #pragma unroll
    for (int mi = 0; mi < 2; mi++)
      #pragma unroll
      for (int ni = 0; ni < 2; ni++) {
        int rl = wm + mi * 16 + ((l >> 4) << 2);
        int cl = wn + ni * 16 + lr;
        float bval = dtb[n0 + cl];
        #pragma unroll
        for (int r = 0; r < 4; r++) {
          float v = acc[mi][ni][r] + bval;
          v = (v > 20.f) ? v : log1pf(__expf(v));
          s_a[rl + r][cl] = __float_as_uint(v);
        }
      }
    __syncthreads();

    // build packed {dt, dt*u} and {gz, u*D*gz} in place (row-major reads)
    {
      int c = tid & 63, r4 = tid >> 6;
      float Dv = dpar[n0 + c];
      #pragma unroll
      for (int k = 0; k < 16; k++) {
        int r = k * 4 + r4;
        float dtv = __uint_as_float(s_a[r][c]);
        float uv  = b2f(ub[(size_t)(m0 + r) * DIN + n0 + c]);
        float zz  = b2f(xz[(size_t)(m0 + r) * NQ + ZOFF + n0 + c]);
        float g = zz / (1.f + __expf(-zz));
        s_a[r][c] = pack_bf2(dtv, dtv * uv);
        s_b[r][c] = pack_bf2(g, uv * Dv * g);
      }
    }
    __syncthreads();

    // transposed coalesced writes: 64 contiguous t per (d) row
    {
      int dl = tid >> 2, q = tid & 3;
      unsigned vd[16], vs[16];
      #pragma unroll
      for (int j = 0; j < 16; j++) {
        vd[j] = s_a[q * 16 + j][dl];
        vs[j] = s_b[q * 16 + j][dl];
      }
      size_t obase = ((size_t)(b * DIN + n0 + dl)) * LL + t0g + q * 16;
      #pragma unroll
      for (int jj = 0; jj < 4; jj++) {
        *(uint4*)&dtu_p[obase + jj * 4] = *(uint4*)&vd[jj * 4];
        *(uint4*)&sg_p [obase + jj * 4] = *(uint4*)&vs[jj * 4];
      }
    }
  } else {
    int i = (id - 1024) * 256 + tid;    // (b, tp, n): BB*1024*64
    int n = i & 63, tp = (i >> 6) & 1023, b = i >> 16;
    size_t r0 = ((size_t)(b * LL + 2 * tp)) * 160;
    float B0 = dbc[r0 + 32 + n],  C0 = dbc[r0 + 96 + n];
    float B1 = dbc[r0 + 192 + n], C1 = dbc[r0 + 256 + n];
    bbp[i] = pack_bf2(B0, B1);
    bcp4[i] = make_float4(B0, C0, B1, C1);
  }
}

// ---------------------------------------------------------------- fused scan phase1 + carry: block = (b,d), 4 waves x 4 chunks
__global__ __launch_bounds__(256) void scan_p1c(
    const unsigned* __restrict__ dtu_p, const unsigned* __restrict__ bbp,
    const float* __restrict__ alog, float* __restrict__ carry)
{
  __shared__ float ldsE[4][TC][2];
  __shared__ float hfL[NCH][NS];
  __shared__ float apL[NCH][NS];
  int tid = threadIdx.x, w = tid >> 6, l = tid & 63;
  int bid = blockIdx.x;
  int d = bid & (DIN - 1);
  int b = bid >> 10;
  float An2 = -__expf(alog[d * NS + l]) * LOG2E;

  for (int k = 0; k < 4; k++) {
    int cc = w * 4 + k;
    size_t pbase = ((size_t)(b * DIN + d)) * LL + cc * TC;
    unsigned p0 = dtu_p[pbase + l];
    unsigned p1 = dtu_p[pbase + 64 + l];
    float s0 = bflo(p0), s1 = bflo(p1);
    s0 = DPP_ADD(s0, 0x111, 0xf); s0 = DPP_ADD(s0, 0x112, 0xf);
    s0 = DPP_ADD(s0, 0x114, 0xf); s0 = DPP_ADD(s0, 0x118, 0xf);
    s0 = DPP_ADD(s0, 0x142, 0xa); s0 = DPP_ADD(s0, 0x143, 0xc);
    s1 = DPP_ADD(s1, 0x111, 0xf); s1 = DPP_ADD(s1, 0x112, 0xf);
    s1 = DPP_ADD(s1, 0x114, 0xf); s1 = DPP_ADD(s1, 0x118, 0xf);
    s1 = DPP_ADD(s1, 0x142, 0xa); s1 = DPP_ADD(s1, 0x143, 0xc);
    float T0 = __uint_as_float(__builtin_amdgcn_readlane(__float_as_uint(s0), 63));
    float T  = T0 + __uint_as_float(__builtin_amdgcn_readlane(__float_as_uint(s1), 63));
    ldsE[w][l][0]      = T - s0;
    ldsE[w][l][1]      = bfhi(p0);
    ldsE[w][64 + l][0] = (T - T0) - s1;
    ldsE[w][64 + l][1] = bfhi(p1);
    // wave-private LDS region: no block barrier needed

    const unsigned* bq = bbp + ((size_t)(b * 1024 + cc * 64) * 64 + l);
    float h0 = 0.f, h1 = 0.f;
    for (int g = 0; g < 16; g++) {
      unsigned bv[4];
      #pragma unroll
      for (int kk = 0; kk < 4; kk++) bv[kk] = bq[kk * 64];
      const float* gb = &ldsE[w][g * 8][0];
      #pragma unroll
      for (int j = 0; j < 8; j++) {
        float2 dd = *(const float2*)(gb + j * 2);
        float Bv = (j & 1) ? bfhi(bv[j >> 1]) : bflo(bv[j >> 1]);
        float a = fexp2(dd.x * An2);
        if (j & 1) h1 += a * (dd.y * Bv);
        else       h0 += a * (dd.y * Bv);
      }
      bq += 256;
    }
    hfL[cc][l] = h0 + h1;
    apL[cc][l] = fexp2(T * An2);
  }
  __syncthreads();

  // carry fold over all 16 chunks (each wave redundantly scans, keeps its 4)
  float cur = 0.f, myc[4];
  #pragma unroll
  for (int cc = 0; cc < NCH; cc++) {
    if ((cc >> 2) == w) myc[cc & 3] = cur;
    cur = apL[cc][l] * cur + hfL[cc][l];
  }
  size_t cbase = ((size_t)((b << 10) + d) * NCH) * 64 + l;
  #pragma unroll
  for (int k = 0; k < 4; k++)
    carry[cbase + (size_t)(w * 4 + k) * 64] = myc[k];
}

// ---------------------------------------------------------------- chunked scan, phase 3
__global__ __launch_bounds__(256) void scan_phase3(
    const unsigned* __restrict__ dtu_p, const unsigned* __restrict__ sg_p,
    const float4* __restrict__ bcp4, const float* __restrict__ alog,
    const float* __restrict__ carry, ushort* __restrict__ ymt)
{
  __shared__ float lds[4][TC][4];
  __shared__ ushort yt[4][TC];
  int tid = threadIdx.x, w = tid >> 6, l = tid & 63;
  int wid = blockIdx.x * 4 + w;
  int d = wid & (DIN - 1);
  int c = (wid >> 10) & (NCH - 1);
  int b = wid >> 14;
  float An2 = -__expf(alog[d * NS + l]) * LOG2E;

  size_t pbase = ((size_t)(b * DIN + d)) * LL + c * TC;
  #pragma unroll
  for (int q = 0; q < 2; q++) {
    unsigned pd = dtu_p[pbase + q * 64 + l];
    unsigned pg = sg_p [pbase + q * 64 + l];
    lds[w][q * 64 + l][0] = bflo(pd);
    lds[w][q * 64 + l][1] = bfhi(pd);
    lds[w][q * 64 + l][2] = bflo(pg);
    lds[w][q * 64 + l][3] = bfhi(pg);
  }
  __syncthreads();

  float h = carry[(((size_t)((b << 10) + d) * NCH) + c) * 64 + l];
  const float4* bq = bcp4 + ((size_t)(b * 1024 + c * 64) * 64 + l);
  bool s1f = l & 1, s2f = l & 2, s4f = l & 4;
  bool wl = l < 8;

  for (int g = 0; g < 16; g++) {
    float4 bcs[4];
    bcs[0] = bq[0]; bcs[1] = bq[64]; bcs[2] = bq[128]; bcs[3] = bq[192];
    const float* gb = &lds[w][g * 8][0];
    float p[8];
    #pragma unroll
    for (int j = 0; j < 8; j++) {
      float2 dd = *(const float2*)(gb + j * 4);
      float Bv = (j & 1) ? bcs[j >> 1].z : bcs[j >> 1].x;
      float Cv = (j & 1) ? bcs[j >> 1].w : bcs[j >> 1].y;
      float a = fexp2(dd.x * An2);
      h = a * h + dd.y * Bv;
      p[j] = h * Cv;
    }
    #pragma unroll
    for (int j = 0; j < 8; j++) p[j] += QP(p[j], 0xB1);       // xor1
    float q0 = s1f ? p[1] : p[0];
    float q1 = s1f ? p[3] : p[2];
    float q2 = s1f ? p[5] : p[4];
    float q3 = s1f ? p[7] : p[6];
    q0 += QP(q0, 0x4E); q1 += QP(q1, 0x4E);                   // xor2
    q2 += QP(q2, 0x4E); q3 += QP(q3, 0x4E);
    float r0 = s2f ? q1 : q0;
    float r1 = s2f ? q3 : q2;
    r0 += SWZ(r0, 0x101F); r1 += SWZ(r1, 0x101F);             // xor4
    float s = s4f ? r1 : r0;
    s += QP(s, 0x128);                                        // xor8 (row_ror:8)
    s += SWZ(s, 0x401F);                                      // xor16
    s = xor32_add_lo(s);                                      // xor32 (permlane)

    float2 sgv = *(const float2*)(&lds[w][g * 8 + (l & 7)][2]);
    if (wl) yt[w][g * 8 + l] = f2b(s * sgv.x + sgv.y);
    bq += 256;
  }
  __syncthreads();
  unsigned vv = *(const unsigned*)&yt[w][2 * l];
  ((unsigned*)(ymt + pbase))[l] = vv;
}

// ---------------------------------------------------------------- transpose ymt[b][d][t] -> comb[b][t][512 + d] (stride NC)
__global__ __launch_bounds__(256) void transpose_ym(
    const ushort* __restrict__ ymt, ushort* __restrict__ comb)
{
  __shared__ ushort tile[64][72];
  int tid = threadIdx.x;
  int bx = blockIdx.x;          // d-tile (DIN/64 = 16)
  int by = blockIdx.y;          // t-tile (LL/64 = 32)
  int b  = blockIdx.z;
  int r = tid >> 2, c16 = (tid & 3) * 16;
  const ushort* src = ymt + ((size_t)(b * DIN + bx * 64 + r)) * LL + by * 64 + c16;
  *(uint4*)&tile[r][c16]     = *(const uint4*)src;
  *(uint4*)&tile[r][c16 + 8] = *(const uint4*)(src + 8);
  __syncthreads();
  ushort tmp[16];
  #pragma unroll
  for (int j = 0; j < 16; j++) tmp[j] = tile[c16 + j][r];
  ushort* dst = comb + ((size_t)(b * LL + by * 64 + r)) * NC + DD + bx * 64 + c16;
  *(uint4*)dst       = *(uint4*)&tmp[0];
  *(uint4*)(dst + 8) = *(uint4*)&tmp[8];
}

// ---------------------------------------------------------------- residual + LayerNorm (x + combined attn+mamba)
__global__ __launch_bounds__(256) void residual_ln(
    const float* __restrict__ x, const float* __restrict__ so,
    const float* __restrict__ lw, const float* __restrict__ lb,
    float* __restrict__ out)
{
  int row = blockIdx.x * 4 + (threadIdx.x >> 6);
  int l = threadIdx.x & 63;
  size_t base = (size_t)row * DD;
  float h[8];
  float s = 0.f, s2 = 0.f;
  #pragma unroll
  for (int half = 0; half < 2; half++) {
    int c = half * 256 + l * 4;
    float4 xv = *(const float4*)(x + base + c);
    float4 sv = *(const float4*)(so + base + c);
    float* hp = h + half * 4;
    hp[0] = xv.x + sv.x;
    hp[1] = xv.y + sv.y;
    hp[2] = xv.z + sv.z;
    hp[3] = xv.w + sv.w;
    #pragma unroll
    for (int j = 0; j < 4; j++) { s += hp[j]; s2 += hp[j] * hp[j]; }
  }
  #pragma unroll
  for (int o = 1; o < 64; o <<= 1) { s += __shfl_xor(s, o); s2 += __shfl_xor(s2, o); }
  float mean = s * (1.f / DD);
  float var = s2 * (1.f / DD) - mean * mean;
  float rs = rsqrtf(var + 1e-5f);
  #pragma unroll
  for (int half = 0; half < 2; half++) {
    int c = half * 256 + l * 4;
    float4 ov;
    ov.x = (h[half*4+0] - mean) * rs * lw[c+0] + lb[c+0];
    ov.y = (h[half*4+1] - mean) * rs * lw[c+1] + lb[c+1];
    ov.z = (h[half*4+2] - mean) * rs * lw[c+2] + lb[c+2];
    ov.w = (h[half*4+3] - mean) * rs * lw[c+3] + lb[c+3];
    *(float4*)(out + base + c) = ov;
  }
}

// ---------------------------------------------------------------- host
extern "C" void kernel_launch(void* const* d_in, const int* in_sizes, int n_in,
                              void* d_out, int out_size, void* d_ws, size_t ws_size,
                              hipStream_t stream) {
  const float* x    = (const float*)d_in[0];
  const float* wq   = (const float*)d_in[1];
  const float* bq   = (const float*)d_in[2];
  const float* wk   = (const float*)d_in[3];
  const float* bk   = (const float*)d_in[4];
  const float* wv   = (const float*)d_in[5];
  const float* bv   = (const float*)d_in[6];
  const float* wo   = (const float*)d_in[7];
  const float* bo   = (const float*)d_in[8];
  const float* inw  = (const float*)d_in[9];
  const float* cw   = (const float*)d_in[10];
  const float* cb   = (const float*)d_in[11];
  const float* xpw  = (const float*)d_in[12];
  const float* dtw  = (const float*)d_in[13];
  const float* dtb  = (const float*)d_in[14];
  const float* alog = (const float*)d_in[15];
  const float* dpar = (const float*)d_in[16];
  const float* opw  = (const float*)d_in[17];
  const float* lnw  = (const float*)d_in[18];
  const float* lnb  = (const float*)d_in[19];

  char* ws = (char*)d_ws;
  size_t off = 0;
  auto alloc = [&](size_t bytes) -> void* {
    void* p = ws + off;
    off += (bytes + 255) & ~(size_t)255;
    return p;
  };

  const size_t BLD = (size_t)BL * DD;
  const size_t BLDIN = (size_t)BL * DIN;

  ushort* xf_b   = (ushort*)alloc(BLD * 2);
  ushort* wqi_b  = (ushort*)alloc((size_t)NQ * DD * 2);      // [qkv | in_proj] weights
  float*  bqi    = (float*)alloc(NQ * 4);
  ushort* xpw_b  = (ushort*)alloc(160 * DIN * 2);
  ushort* dtw_b  = (ushort*)alloc(DIN * RR * 2);
  ushort* wcomb_b= (ushort*)alloc((size_t)DD * NC * 2);
  ushort* qkvxz_b= (ushort*)alloc((size_t)BL * NQ * 2);      // 28.7 MB merged
  ushort* comb_a = (ushort*)alloc((size_t)BL * NC * 2);
  float*  sum_o  = (float*)alloc(BLD * 4);
  ushort* u_b    = (ushort*)alloc(BLDIN * 2);
  float*  dbc    = (float*)alloc((size_t)BL * 160 * 4);
  ushort* ymt_b  = (ushort*)alloc(BLDIN * 2);
  unsigned* bbp  = (unsigned*)alloc((size_t)BB * (LL / 2) * NS * 4);
  float4* bcp4   = (float4*)alloc((size_t)BB * (LL / 2) * NS * sizeof(float4));
  unsigned* dtu_p = (unsigned*)alloc(BLDIN * 4);
  unsigned* sg_p  = (unsigned*)alloc(BLDIN * 4);
  const size_t SCN = (size_t)BB * DIN * NCH * 64;
  float* carry_s = (float*)alloc(SCN * 4);

  // 1) convert inputs to bf16 (qkv + in_proj weights concatenated along N)
  CvtJobs cj;
  cj.src[0] = x;    cj.dst[0] = xf_b;                cj.n[0] = (int)BLD;
  cj.src[1] = wq;   cj.dst[1] = wqi_b;               cj.n[1] = DD * DD;
  cj.src[2] = wk;   cj.dst[2] = wqi_b + DD * DD;     cj.n[2] = DD * DD;
  cj.src[3] = wv;   cj.dst[3] = wqi_b + 2 * DD * DD; cj.n[3] = DD * DD;
  cj.src[4] = inw;  cj.dst[4] = wqi_b + 3 * DD * DD; cj.n[4] = 2 * DIN * DD;
  cj.src[5] = xpw;  cj.dst[5] = xpw_b;               cj.n[5] = 160 * DIN;
  cj.src[6] = dtw;  cj.dst[6] = dtw_b;               cj.n[6] = DIN * RR;
  cvt_multi<<<dim3(256, 7), 256, 0, stream>>>(cj);
  pack_wcomb<<<dim3((DD * NC + 255) / 256), 256, 0, stream>>>(wo, opw, bq, bk, bv, wcomb_b, bqi);

  // 2) merged qkv + in_proj projection (N=3584), global_load_lds staging
  gemm128<<<dim3(28, 32), 256, 0, stream>>>(xf_b, wqi_b, bqi, nullptr, qkvxz_b, BL, NQ, DD);

  // 3) depthwise conv + SiLU (sliding window, 8 t per thread)
  conv_silu<<<dim3(2048), 256, 0, stream>>>(qkvxz_b, cw, cb, u_b);

  // 4) fused: flash attention (512 blocks) || x_proj GEMM (192 blocks)
  attn_xproj<<<dim3(704), 256, 0, stream>>>(qkvxz_b, comb_a, u_b, xpw_b, dbc);

  // 5) fused: dt_proj+softplus+time-major pack (1024 blocks) || pack B/C (512 blocks)
  dt_bc<<<dim3(1536), 256, 0, stream>>>(dbc, dtw_b, dtb, dpar, u_b, qkvxz_b,
                                        dtu_p, sg_p, bbp, bcp4);

  // 6) chunked selective scan: [phase1+carry fused] then phase3
  scan_p1c<<<dim3(BB * DIN), 256, 0, stream>>>(dtu_p, bbp, alog, carry_s);
  scan_phase3<<<dim3(8192), 256, 0, stream>>>(dtu_p, sg_p, bcp4, alog, carry_s, ymt_b);
  transpose_ym<<<dim3(16, 32, BB), 256, 0, stream>>>(ymt_b, comb_a);

  // 7) combined wo-proj + out_proj via 64-tile GEMM (512 blocks, full tiles)
  gemm_bt<<<dim3(8, 64), 256, 0, stream>>>(comb_a, wcomb_b, bo, sum_o, nullptr, BL, DD, NC, 0);

  // 8) residual + LayerNorm
  residual_ln<<<dim3(1024), 256, 0, stream>>>(x, sum_o, lnw, lnb, (float*)d_out);
}

// Round 18
// 334.027 us; speedup vs baseline: 1.1368x; 1.0126x over previous
//
#include <hip/hip_runtime.h>

typedef __attribute__((ext_vector_type(4))) float f32x4;
typedef __attribute__((ext_vector_type(8))) short short8;
typedef __attribute__((ext_vector_type(2))) unsigned uint2e;

#define DEV static __device__ __forceinline__

DEV ushort f2b(float f) {
  union { float f; unsigned u; } v; v.f = f;
  unsigned r = v.u + 0x7FFF + ((v.u >> 16) & 1);
  return (ushort)(r >> 16);
}
DEV unsigned pack_bf2(float lo, float hi) {
  return (unsigned)f2b(lo) | ((unsigned)f2b(hi) << 16);
}
DEV float bflo(unsigned p) { return __uint_as_float(p << 16); }
DEV float bfhi(unsigned p) { return __uint_as_float(p & 0xFFFF0000u); }
DEV float b2f(ushort u) { return __uint_as_float((unsigned)u << 16); }

// raw v_exp_f32 (2^x), no OCML denorm fixup sequence
DEV float fexp2(float x) { float r; asm("v_exp_f32 %0, %1" : "=v"(r) : "v"(x)); return r; }

// lanes 0-31 get s[lane] + s[lane+32] (hi lanes garbage — callers use lanes <8)
DEV float xor32_add_lo(float s) {
  uint2e r = __builtin_amdgcn_permlane32_swap(__float_as_uint(s), __float_as_uint(s), false, false);
  return s + __uint_as_float(r.x);
}

// async global->LDS, 16B per lane; LDS dest = wave-uniform base + lane*16
DEV void gl_lds16(const ushort* g, ushort* l) {
  __builtin_amdgcn_global_load_lds(
      (const __attribute__((address_space(1))) unsigned int*)g,
      (__attribute__((address_space(3))) unsigned int*)l, 16, 0, 0);
}

// DPP helpers (quad_perm / row_ror / row_bcast) and ds_swizzle xor
#define QP(x, ctrl) __int_as_float(__builtin_amdgcn_update_dpp(0, __float_as_int(x), (ctrl), 0xf, 0xf, false))
#define SWZ(x, off) __int_as_float(__builtin_amdgcn_ds_swizzle(__float_as_int(x), (off)))
#define DPP_ADD(x, ctrl, rmask) \
  ((x) + __int_as_float(__builtin_amdgcn_update_dpp(0, __float_as_int(x), (ctrl), (rmask), 0xf, false)))

#define LOG2E 1.44269504f

// ---------------------------------------------------------------- constants
#define BB    2
#define LL    2048
#define DD    512
#define HH    8
#define EE    64
#define DIN   1024
#define NS    64
#define RR    32
#define BL    4096            // B*L
#define NCH   16              // scan chunks
#define TC    128             // steps per chunk (LL/NCH)
#define NC    1536            // comb width (ctx | ym)
#define NQ    3584            // merged qkv+xz width
#define XOFF  1536            // x_in column offset in merged buffer
#define ZOFF  2560            // z column offset
#define MFMA(a,b,c) __builtin_amdgcn_mfma_f32_16x16x32_bf16((a),(b),(c),0,0,0)

// ---------------------------------------------------------------- f32 -> bf16 multi-convert
struct CvtJobs {
  const float* src[7];
  ushort*      dst[7];
  int          n[7];
};

__global__ __launch_bounds__(256) void cvt_multi(CvtJobs j) {
  int job = blockIdx.y;
  const float* s = j.src[job];
  ushort* d = j.dst[job];
  int n = j.n[job];
  for (int i = blockIdx.x * 256 + threadIdx.x; i < n; i += gridDim.x * 256)
    d[i] = f2b(s[i]);
}

// ---------------------------------------------------------------- pack combined [wo | out_proj] weight + merged bias
__global__ __launch_bounds__(256) void pack_wcomb(
    const float* __restrict__ wo, const float* __restrict__ opw,
    const float* __restrict__ bq, const float* __restrict__ bk,
    const float* __restrict__ bv, ushort* __restrict__ wc,
    float* __restrict__ bqi)
{
  int i = blockIdx.x * 256 + threadIdx.x;   // 512*1536
  if (i < NQ)
    bqi[i] = (i < DD) ? bq[i] : (i < 2 * DD) ? bk[i - DD] : (i < NC) ? bv[i - 2 * DD] : 0.f;
  if (i >= DD * NC) return;
  int n = i / NC, c = i - n * NC;
  float v = (c < DD) ? wo[n * DD + c] : opw[n * DIN + (c - DD)];
  wc[i] = f2b(v);
}

// ---------------------------------------------------------------- GEMM 64-tile, global_load_lds staging (full tiles only)
__global__ __launch_bounds__(256) void gemm_bt(
    const ushort* __restrict__ A, const ushort* __restrict__ W,
    const float* __restrict__ bias, float* __restrict__ outF,
    ushort* __restrict__ outB, int M, int N, int K, int act)
{
  __shared__ ushort As[64 * 32];
  __shared__ ushort Ws[64 * 32];
  int m0 = blockIdx.y * 64, n0 = blockIdx.x * 64;
  int tid = threadIdx.x, l = tid & 63, w = tid >> 6;
  int wm = (w >> 1) * 32, wn = (w & 1) * 32;
  int lr = l & 15, kl = (l >> 4) * 8;
  int srow = w * 16 + (l >> 2), scol = (l & 3) * 8;
  const ushort* gA = A + (size_t)(m0 + srow) * K + scol;
  const ushort* gW = W + (size_t)(n0 + srow) * K + scol;
  ushort* lA = As + w * 512;
  ushort* lW = Ws + w * 512;
  f32x4 acc[2][2] = {};

  for (int k0 = 0; k0 < K; k0 += 32) {
    __syncthreads();
    gl_lds16(gA, lA);
    gl_lds16(gW, lW);
    __syncthreads();
    short8 a0 = *(const short8*)&As[(wm + lr) * 32 + kl];
    short8 a1 = *(const short8*)&As[(wm + 16 + lr) * 32 + kl];
    short8 b0 = *(const short8*)&Ws[(wn + lr) * 32 + kl];
    short8 b1 = *(const short8*)&Ws[(wn + 16 + lr) * 32 + kl];
    acc[0][0] = MFMA(a0, b0, acc[0][0]);
    acc[0][1] = MFMA(a0, b1, acc[0][1]);
    acc[1][0] = MFMA(a1, b0, acc[1][0]);
    acc[1][1] = MFMA(a1, b1, acc[1][1]);
    gA += 32; gW += 32;
  }

  #pragma unroll
  for (int mi = 0; mi < 2; mi++)
    #pragma unroll
    for (int ni = 0; ni < 2; ni++) {
      int rbase = m0 + wm + mi * 16 + ((l >> 4) << 2);
      int col = n0 + wn + ni * 16 + lr;
      float bval = bias ? bias[col] : 0.f;
      #pragma unroll
      for (int r = 0; r < 4; r++) {
        float v = acc[mi][ni][r] + bval;
        if (act == 1) v = (v > 20.f) ? v : log1pf(__expf(v));
        size_t o = (size_t)(rbase + r) * N + col;
        if (outF) outF[o] = v;
        if (outB) outB[o] = f2b(v);
      }
    }
}

// ---------------------------------------------------------------- GEMM 128-tile, global_load_lds staging (M,N mult of 128, K mult of 32)
__global__ __launch_bounds__(256) void gemm128(
    const ushort* __restrict__ A, const ushort* __restrict__ W,
    const float* __restrict__ bias, float* __restrict__ outF,
    ushort* __restrict__ outB, int M, int N, int K)
{
  __shared__ ushort As[128 * 32];
  __shared__ ushort Ws[128 * 32];
  int tid = threadIdx.x, l = tid & 63, w = tid >> 6;
  int m0 = blockIdx.y * 128, n0 = blockIdx.x * 128;
  int wm = (w >> 1) * 64, wn = (w & 1) * 64;
  int lr = l & 15, kl = (l >> 4) * 8;
  f32x4 acc[4][4] = {};

  int srow = w * 32 + (l >> 2), scol = (l & 3) * 8;
  const ushort* gA0 = A + (size_t)(m0 + srow) * K + scol;
  const ushort* gA1 = gA0 + (size_t)16 * K;
  const ushort* gW0 = W + (size_t)(n0 + srow) * K + scol;
  const ushort* gW1 = gW0 + (size_t)16 * K;
  ushort* lA0 = As + w * 1024;
  ushort* lA1 = As + w * 1024 + 512;
  ushort* lW0 = Ws + w * 1024;
  ushort* lW1 = Ws + w * 1024 + 512;

  for (int k0 = 0; k0 < K; k0 += 32) {
    __syncthreads();
    gl_lds16(gA0, lA0);
    gl_lds16(gA1, lA1);
    gl_lds16(gW0, lW0);
    gl_lds16(gW1, lW1);
    __syncthreads();
    short8 af[4], bf[4];
    #pragma unroll
    for (int mi = 0; mi < 4; mi++) af[mi] = *(const short8*)&As[(wm + mi * 16 + lr) * 32 + kl];
    #pragma unroll
    for (int ni = 0; ni < 4; ni++) bf[ni] = *(const short8*)&Ws[(wn + ni * 16 + lr) * 32 + kl];
    #pragma unroll
    for (int mi = 0; mi < 4; mi++)
      #pragma unroll
      for (int ni = 0; ni < 4; ni++)
        acc[mi][ni] = MFMA(af[mi], bf[ni], acc[mi][ni]);
    gA0 += 32; gA1 += 32; gW0 += 32; gW1 += 32;
  }

  #pragma unroll
  for (int mi = 0; mi < 4; mi++)
    #pragma unroll
    for (int ni = 0; ni < 4; ni++) {
      int rbase = m0 + wm + mi * 16 + ((l >> 4) << 2);
      int col = n0 + wn + ni * 16 + lr;
      float bval = bias ? bias[col] : 0.f;
      #pragma unroll
      for (int r = 0; r < 4; r++) {
        float v = acc[mi][ni][r] + bval;
        size_t o = (size_t)(rbase + r) * N + col;
        if (outF) outF[o] = v;
        if (outB) outB[o] = f2b(v);
      }
    }
}

// ---------------------------------------------------------------- fused: flash attention (blocks 0..511, double-buffered K/V + async stage)
//                                                                   || x_proj GEMM (blocks 512..703)
__global__ __launch_bounds__(256) void attn_xproj(
    const ushort* __restrict__ qkv, ushort* __restrict__ comb,
    const ushort* __restrict__ ub, const ushort* __restrict__ xpw,
    float* __restrict__ dbc)
{
  __shared__ ushort smem[6 * 64 * 72];     // 55.3 KB (attn), union w/ xproj
  int id = blockIdx.x;
  int tid = threadIdx.x, l = tid & 63, w = tid >> 6;

  if (id < 512) {
    // ---------------- flash attention, no-max log2 softmax, T14 async stage ----------------
    typedef ushort row72[72];
    row72* Qs  = (row72*)smem;
    row72* Ps  = Qs + 64;
    row72* Kb0 = Ps + 64;
    row72* Vb0 = Kb0 + 64;
    row72* Kb1 = Vb0 + 64;
    row72* Vb1 = Kb1 + 64;
    int qt = 31 - (id & 31), h = (id >> 5) & 7, b = id >> 8;
    int w16 = w * 16, lr = l & 15, kl = (l >> 4) * 8;

    // staging coords: this thread handles rows s_r0 = tid>>3 stepping +32, col c8
    int s_r0 = tid >> 3, c8 = (tid & 7) * 8;
    int s_r1 = s_r0 + 32;

    for (int i = tid; i < 512; i += 256) {
      int row = i >> 3, cc = (i & 7) * 8;
      *(uint4*)&Qs[row][cc] =
          *(const uint4*)&qkv[((size_t)(b * LL + qt * 64 + row)) * NQ + h * EE + cc];
    }

    // prologue: load tile 0 into regs, write buf0
    uint4 kr0, kr1, vr0, vr1;
    {
      size_t rb0 = ((size_t)(b * LL + s_r0)) * NQ + h * EE + c8;
      size_t rb1 = ((size_t)(b * LL + s_r1)) * NQ + h * EE + c8;
      kr0 = *(const uint4*)&qkv[rb0 + DD];
      vr0 = *(const uint4*)&qkv[rb0 + 2 * DD];
      kr1 = *(const uint4*)&qkv[rb1 + DD];
      vr1 = *(const uint4*)&qkv[rb1 + 2 * DD];
    }
    {
      *(uint4*)&Kb0[s_r0][c8] = kr0;
      *(uint4*)&Kb0[s_r1][c8] = kr1;
      const ushort* p0 = (const ushort*)&vr0;
      const ushort* p1 = (const ushort*)&vr1;
      #pragma unroll
      for (int jj = 0; jj < 8; jj++) {
        Vb0[c8 + jj][s_r0] = p0[jj];
        Vb0[c8 + jj][s_r1] = p1[jj];
      }
    }
    __syncthreads();

    float l_r[4] = {0.f, 0.f, 0.f, 0.f};
    f32x4 oacc[4] = {};
    const float SSC = 0.125f * LOG2E;
    int cur = 0;

    for (int kv = 0; kv <= qt; kv++) {
      // async-issue next tile's loads into regs (latency hides under compute)
      if (kv < qt) {
        size_t rb0 = ((size_t)(b * LL + (kv + 1) * 64 + s_r0)) * NQ + h * EE + c8;
        size_t rb1 = ((size_t)(b * LL + (kv + 1) * 64 + s_r1)) * NQ + h * EE + c8;
        kr0 = *(const uint4*)&qkv[rb0 + DD];
        vr0 = *(const uint4*)&qkv[rb0 + 2 * DD];
        kr1 = *(const uint4*)&qkv[rb1 + DD];
        vr1 = *(const uint4*)&qkv[rb1 + 2 * DD];
      }
      row72* Ks = cur ? Kb1 : Kb0;
      row72* Vt = cur ? Vb1 : Vb0;

      f32x4 sacc[4] = {};
      __builtin_amdgcn_s_setprio(1);
      #pragma unroll
      for (int kk = 0; kk < 2; kk++) {
        short8 aq = *(const short8*)&Qs[w16 + lr][kk * 32 + kl];
        #pragma unroll
        for (int nt = 0; nt < 4; nt++) {
          short8 bk8 = *(const short8*)&Ks[nt * 16 + lr][kk * 32 + kl];
          sacc[nt] = MFMA(aq, bk8, sacc[nt]);
        }
      }
      __builtin_amdgcn_s_setprio(0);

      bool diag = (kv == qt);
      #pragma unroll
      for (int r = 0; r < 4; r++) {
        int rloc = w16 + ((l >> 4) << 2) + r;
        float rs = 0.f;
        #pragma unroll
        for (int nt = 0; nt < 4; nt++) {
          float v = sacc[nt][r] * SSC;
          if (diag && (nt * 16 + lr) > rloc) v = -1e30f;
          float p = fexp2(v);
          rs += p;
          Ps[rloc][nt * 16 + lr] = f2b(p);
        }
        rs += QP(rs, 0xB1);
        rs += QP(rs, 0x4E);
        rs += SWZ(rs, 0x101F);
        rs += SWZ(rs, 0x201F);
        l_r[r] += rs;
      }

      __builtin_amdgcn_s_setprio(1);
      #pragma unroll
      for (int kk = 0; kk < 2; kk++) {
        short8 ap = *(const short8*)&Ps[w16 + lr][kk * 32 + kl];
        #pragma unroll
        for (int nt = 0; nt < 4; nt++) {
          short8 bv8 = *(const short8*)&Vt[nt * 16 + lr][kk * 32 + kl];
          oacc[nt] = MFMA(ap, bv8, oacc[nt]);
        }
      }
      __builtin_amdgcn_s_setprio(0);

      // write next tile into the other buffer (no conflict with cur readers)
      if (kv < qt) {
        row72* Kn = cur ? Kb0 : Kb1;
        row72* Vn = cur ? Vb0 : Vb1;
        *(uint4*)&Kn[s_r0][c8] = kr0;
        *(uint4*)&Kn[s_r1][c8] = kr1;
        const ushort* p0 = (const ushort*)&vr0;
        const ushort* p1 = (const ushort*)&vr1;
        #pragma unroll
        for (int jj = 0; jj < 8; jj++) {
          Vn[c8 + jj][s_r0] = p0[jj];
          Vn[c8 + jj][s_r1] = p1[jj];
        }
      }
      __syncthreads();
      cur ^= 1;
    }

    #pragma unroll
    for (int nt = 0; nt < 4; nt++)
      #pragma unroll
      for (int r = 0; r < 4; r++) {
        int row = qt * 64 + w16 + ((l >> 4) << 2) + r;
        float v = oacc[nt][r] / l_r[r];
        comb[((size_t)(b * LL + row)) * NC + h * EE + nt * 16 + lr] = f2b(v);
      }
  } else {
    // ---------------- x_proj: dbc = u @ xpw^T  (M=BL, N=160, K=DIN) ----------------
    typedef ushort row40[40];
    row40* As = (row40*)smem;
    row40* Ws = As + 64;
    int rid = id - 512;                 // 192 blocks = 3 x 64
    int n0 = (rid % 3) * 64, m0 = (rid / 3) * 64;
    int wm = (w >> 1) * 32, wn = (w & 1) * 32;
    int lr = l & 15, kl = (l >> 4) * 8;
    int srow = tid >> 2, sk = (tid & 3) * 8;
    f32x4 acc[2][2] = {};

    for (int k0 = 0; k0 < DIN; k0 += 32) {
      uint4 av = *(const uint4*)&ub[(size_t)(m0 + srow) * DIN + k0 + sk];
      uint4 wv;
      if (n0 + srow < 160) wv = *(const uint4*)&xpw[(size_t)(n0 + srow) * DIN + k0 + sk];
      else { wv.x = 0; wv.y = 0; wv.z = 0; wv.w = 0; }
      *(uint4*)&As[srow][sk] = av;
      *(uint4*)&Ws[srow][sk] = wv;
      __syncthreads();
      short8 a0 = *(const short8*)&As[wm + lr][kl];
      short8 a1 = *(const short8*)&As[wm + 16 + lr][kl];
      short8 b0 = *(const short8*)&Ws[wn + lr][kl];
      short8 b1 = *(const short8*)&Ws[wn + 16 + lr][kl];
      acc[0][0] = MFMA(a0, b0, acc[0][0]);
      acc[0][1] = MFMA(a0, b1, acc[0][1]);
      acc[1][0] = MFMA(a1, b0, acc[1][0]);
      acc[1][1] = MFMA(a1, b1, acc[1][1]);
      __syncthreads();
    }

    #pragma unroll
    for (int mi = 0; mi < 2; mi++)
      #pragma unroll
      for (int ni = 0; ni < 2; ni++) {
        int rbase = m0 + wm + mi * 16 + ((l >> 4) << 2);
        int col = n0 + wn + ni * 16 + lr;
        if (col < 160) {
          #pragma unroll
          for (int r = 0; r < 4; r++)
            dbc[(size_t)(rbase + r) * 160 + col] = acc[mi][ni][r];
        }
      }
  }
}

// ---------------------------------------------------------------- depthwise causal conv (K=4) + SiLU: sliding window, 8 t per thread
__global__ __launch_bounds__(256) void conv_silu(
    const ushort* __restrict__ xz, const float* __restrict__ cw,
    const float* __restrict__ cb, ushort* __restrict__ ub)
{
  int i = blockIdx.x * 256 + threadIdx.x;        // (BL/8)*DIN threads
  int d = i & (DIN - 1);
  int r = i >> 10;
  int t0 = (r & (LL / 8 - 1)) * 8;
  int b = r >> 8;
  float c0 = cw[d * 4], c1 = cw[d * 4 + 1], c2 = cw[d * 4 + 2], c3 = cw[d * 4 + 3];
  float bias = cb[d];
  float xw[11];
  #pragma unroll
  for (int j = 0; j < 3; j++) {
    int tt = t0 - 3 + j;
    xw[j] = (tt >= 0) ? b2f(xz[((size_t)(b * LL + tt)) * NQ + XOFF + d]) : 0.f;
  }
  #pragma unroll
  for (int j = 0; j < 8; j++)
    xw[3 + j] = b2f(xz[((size_t)(b * LL + t0 + j)) * NQ + XOFF + d]);
  size_t obase = (size_t)(b * LL + t0) * DIN + d;
  #pragma unroll
  for (int j = 0; j < 8; j++) {
    float s = bias + xw[j] * c0 + xw[j + 1] * c1 + xw[j + 2] * c2 + xw[j + 3] * c3;
    ub[obase + (size_t)j * DIN] = f2b(s / (1.f + __expf(-s)));
  }
}

// ---------------------------------------------------------------- fused: dt_proj GEMM + time-major pack (blocks 0..1023) || pack B,C (blocks 1024..1535)
__global__ __launch_bounds__(256) void dt_bc(
    const float* __restrict__ dbc, const ushort* __restrict__ dtw,
    const float* __restrict__ dtb, const float* __restrict__ dpar,
    const ushort* __restrict__ ub, const ushort* __restrict__ xz,
    unsigned* __restrict__ dtu_p, unsigned* __restrict__ sg_p,
    unsigned* __restrict__ bbp, float4* __restrict__ bcp4)
{
  __shared__ ushort As[64][40];
  __shared__ ushort Ws[64][40];
  __shared__ unsigned s_a[64][65];
  __shared__ unsigned s_b[64][65];
  int id = blockIdx.x;
  int tid = threadIdx.x;
  if (id < 1024) {
    int m0 = (id >> 4) * 64, n0 = (id & 15) * 64;
    int b = m0 >> 11, t0g = m0 & (LL - 1);
    int l = tid & 63, w = tid >> 6;
    int wm = (w >> 1) * 32, wn = (w & 1) * 32;
    int lr = l & 15, kl = (l >> 4) * 8;
    int srow = tid >> 2, sk = (tid & 3) * 8;

    const float* ar = dbc + (size_t)(m0 + srow) * 160 + sk;
    short8 av;
    #pragma unroll
    for (int j = 0; j < 8; j++) ((ushort*)&av)[j] = f2b(ar[j]);
    *(short8*)&As[srow][sk] = av;
    *(uint4*)&Ws[srow][sk] = *(const uint4*)&dtw[(size_t)(n0 + srow) * RR + sk];
    __syncthreads();

    f32x4 acc[2][2] = {};
    short8 a0 = *(const short8*)&As[wm + lr][kl];
    short8 a1 = *(const short8*)&As[wm + 16 + lr][kl];
    short8 b0 = *(const short8*)&Ws[wn + lr][kl];
    short8 b1 = *(const short8*)&Ws[wn + 16 + lr][kl];
    acc[0][0] = MFMA(a0, b0, acc[0][0]);
    acc[0][1] = MFMA(a0, b1, acc[0][1]);
    acc[1][0] = MFMA(a1, b0, acc[1][0]);
    acc[1][1] = MFMA(a1, b1, acc[1][1]);

    // softplus, stash dt (f32 bits) in LDS at [t_local][d_local]
    #pragma unroll
    for (int mi = 0; mi < 2; mi++)
      #pragma unroll
      for (int ni = 0; ni < 2; ni++) {
        int rl = wm + mi * 16 + ((l >> 4) << 2);
        int cl = wn + ni * 16 + lr;
        float bval = dtb[n0 + cl];
        #pragma unroll
        for (int r = 0; r < 4; r++) {
          float v = acc[mi][ni][r] + bval;
          v = (v > 20.f) ? v : log1pf(__expf(v));
          s_a[rl + r][cl] = __float_as_uint(v);
        }
      }
    __syncthreads();

    // build packed {dt, dt*u} and {gz, u*D*gz} in place (row-major reads)
    {
      int c = tid & 63, r4 = tid >> 6;
      float Dv = dpar[n0 + c];
      #pragma unroll
      for (int k = 0; k < 16; k++) {
        int r = k * 4 + r4;
        float dtv = __uint_as_float(s_a[r][c]);
        float uv  = b2f(ub[(size_t)(m0 + r) * DIN + n0 + c]);
        float zz  = b2f(xz[(size_t)(m0 + r) * NQ + ZOFF + n0 + c]);
        float g = zz / (1.f + __expf(-zz));
        s_a[r][c] = pack_bf2(dtv, dtv * uv);
        s_b[r][c] = pack_bf2(g, uv * Dv * g);
      }
    }
    __syncthreads();

    // transposed coalesced writes: 64 contiguous t per (d) row
    {
      int dl = tid >> 2, q = tid & 3;
      unsigned vd[16], vs[16];
      #pragma unroll
      for (int j = 0; j < 16; j++) {
        vd[j] = s_a[q * 16 + j][dl];
        vs[j] = s_b[q * 16 + j][dl];
      }
      size_t obase = ((size_t)(b * DIN + n0 + dl)) * LL + t0g + q * 16;
      #pragma unroll
      for (int jj = 0; jj < 4; jj++) {
        *(uint4*)&dtu_p[obase + jj * 4] = *(uint4*)&vd[jj * 4];
        *(uint4*)&sg_p [obase + jj * 4] = *(uint4*)&vs[jj * 4];
      }
    }
  } else {
    int i = (id - 1024) * 256 + tid;    // (b, tp, n): BB*1024*64
    int n = i & 63, tp = (i >> 6) & 1023, b = i >> 16;
    size_t r0 = ((size_t)(b * LL + 2 * tp)) * 160;
    float B0 = dbc[r0 + 32 + n],  C0 = dbc[r0 + 96 + n];
    float B1 = dbc[r0 + 192 + n], C1 = dbc[r0 + 256 + n];
    bbp[i] = pack_bf2(B0, B1);
    bcp4[i] = make_float4(B0, C0, B1, C1);
  }
}

// ---------------------------------------------------------------- fused scan phase1 + carry: block = (b,d), 4 waves x 4 chunks
__global__ __launch_bounds__(256) void scan_p1c(
    const unsigned* __restrict__ dtu_p, const unsigned* __restrict__ bbp,
    const float* __restrict__ alog, float* __restrict__ carry)
{
  __shared__ float ldsE[4][TC][2];
  __shared__ float hfL[NCH][NS];
  __shared__ float apL[NCH][NS];
  int tid = threadIdx.x, w = tid >> 6, l = tid & 63;
  int bid = blockIdx.x;
  int d = bid & (DIN - 1);
  int b = bid >> 10;
  float An2 = -__expf(alog[d * NS + l]) * LOG2E;

  for (int k = 0; k < 4; k++) {
    int cc = w * 4 + k;
    size_t pbase = ((size_t)(b * DIN + d)) * LL + cc * TC;
    unsigned p0 = dtu_p[pbase + l];
    unsigned p1 = dtu_p[pbase + 64 + l];
    float s0 = bflo(p0), s1 = bflo(p1);
    s0 = DPP_ADD(s0, 0x111, 0xf); s0 = DPP_ADD(s0, 0x112, 0xf);
    s0 = DPP_ADD(s0, 0x114, 0xf); s0 = DPP_ADD(s0, 0x118, 0xf);
    s0 = DPP_ADD(s0, 0x142, 0xa); s0 = DPP_ADD(s0, 0x143, 0xc);
    s1 = DPP_ADD(s1, 0x111, 0xf); s1 = DPP_ADD(s1, 0x112, 0xf);
    s1 = DPP_ADD(s1, 0x114, 0xf); s1 = DPP_ADD(s1, 0x118, 0xf);
    s1 = DPP_ADD(s1, 0x142, 0xa); s1 = DPP_ADD(s1, 0x143, 0xc);
    float T0 = __uint_as_float(__builtin_amdgcn_readlane(__float_as_uint(s0), 63));
    float T  = T0 + __uint_as_float(__builtin_amdgcn_readlane(__float_as_uint(s1), 63));
    ldsE[w][l][0]      = T - s0;
    ldsE[w][l][1]      = bfhi(p0);
    ldsE[w][64 + l][0] = (T - T0) - s1;
    ldsE[w][64 + l][1] = bfhi(p1);
    // wave-private LDS region: no block barrier needed

    const unsigned* bq = bbp + ((size_t)(b * 1024 + cc * 64) * 64 + l);
    float h0 = 0.f, h1 = 0.f;
    for (int g = 0; g < 16; g++) {
      unsigned bv[4];
      #pragma unroll
      for (int kk = 0; kk < 4; kk++) bv[kk] = bq[kk * 64];
      const float* gb = &ldsE[w][g * 8][0];
      #pragma unroll
      for (int j = 0; j < 8; j++) {
        float2 dd = *(const float2*)(gb + j * 2);
        float Bv = (j & 1) ? bfhi(bv[j >> 1]) : bflo(bv[j >> 1]);
        float a = fexp2(dd.x * An2);
        if (j & 1) h1 += a * (dd.y * Bv);
        else       h0 += a * (dd.y * Bv);
      }
      bq += 256;
    }
    hfL[cc][l] = h0 + h1;
    apL[cc][l] = fexp2(T * An2);
  }
  __syncthreads();

  // carry fold over all 16 chunks (each wave redundantly scans, keeps its 4)
  float cur = 0.f, myc[4];
  #pragma unroll
  for (int cc = 0; cc < NCH; cc++) {
    if ((cc >> 2) == w) myc[cc & 3] = cur;
    cur = apL[cc][l] * cur + hfL[cc][l];
  }
  size_t cbase = ((size_t)((b << 10) + d) * NCH) * 64 + l;
  #pragma unroll
  for (int k = 0; k < 4; k++)
    carry[cbase + (size_t)(w * 4 + k) * 64] = myc[k];
}

// ---------------------------------------------------------------- chunked scan, phase 3
__global__ __launch_bounds__(256) void scan_phase3(
    const unsigned* __restrict__ dtu_p, const unsigned* __restrict__ sg_p,
    const float4* __restrict__ bcp4, const float* __restrict__ alog,
    const float* __restrict__ carry, ushort* __restrict__ ymt)
{
  __shared__ float lds[4][TC][4];
  __shared__ ushort yt[4][TC];
  int tid = threadIdx.x, w = tid >> 6, l = tid & 63;
  int wid = blockIdx.x * 4 + w;
  int d = wid & (DIN - 1);
  int c = (wid >> 10) & (NCH - 1);
  int b = wid >> 14;
  float An2 = -__expf(alog[d * NS + l]) * LOG2E;

  size_t pbase = ((size_t)(b * DIN + d)) * LL + c * TC;
  #pragma unroll
  for (int q = 0; q < 2; q++) {
    unsigned pd = dtu_p[pbase + q * 64 + l];
    unsigned pg = sg_p [pbase + q * 64 + l];
    lds[w][q * 64 + l][0] = bflo(pd);
    lds[w][q * 64 + l][1] = bfhi(pd);
    lds[w][q * 64 + l][2] = bflo(pg);
    lds[w][q * 64 + l][3] = bfhi(pg);
  }
  __syncthreads();

  float h = carry[(((size_t)((b << 10) + d) * NCH) + c) * 64 + l];
  const float4* bq = bcp4 + ((size_t)(b * 1024 + c * 64) * 64 + l);
  bool s1f = l & 1, s2f = l & 2, s4f = l & 4;
  bool wl = l < 8;

  for (int g = 0; g < 16; g++) {
    float4 bcs[4];
    bcs[0] = bq[0]; bcs[1] = bq[64]; bcs[2] = bq[128]; bcs[3] = bq[192];
    const float* gb = &lds[w][g * 8][0];
    float p[8];
    #pragma unroll
    for (int j = 0; j < 8; j++) {
      float2 dd = *(const float2*)(gb + j * 4);
      float Bv = (j & 1) ? bcs[j >> 1].z : bcs[j >> 1].x;
      float Cv = (j & 1) ? bcs[j >> 1].w : bcs[j >> 1].y;
      float a = fexp2(dd.x * An2);
      h = a * h + dd.y * Bv;
      p[j] = h * Cv;
    }
    #pragma unroll
    for (int j = 0; j < 8; j++) p[j] += QP(p[j], 0xB1);       // xor1
    float q0 = s1f ? p[1] : p[0];
    float q1 = s1f ? p[3] : p[2];
    float q2 = s1f ? p[5] : p[4];
    float q3 = s1f ? p[7] : p[6];
    q0 += QP(q0, 0x4E); q1 += QP(q1, 0x4E);                   // xor2
    q2 += QP(q2, 0x4E); q3 += QP(q3, 0x4E);
    float r0 = s2f ? q1 : q0;
    float r1 = s2f ? q3 : q2;
    r0 += SWZ(r0, 0x101F); r1 += SWZ(r1, 0x101F);             // xor4
    float s = s4f ? r1 : r0;
    s += QP(s, 0x128);                                        // xor8 (row_ror:8)
    s += SWZ(s, 0x401F);                                      // xor16
    s = xor32_add_lo(s);                                      // xor32 (permlane)

    float2 sgv = *(const float2*)(&lds[w][g * 8 + (l & 7)][2]);
    if (wl) yt[w][g * 8 + l] = f2b(s * sgv.x + sgv.y);
    bq += 256;
  }
  __syncthreads();
  unsigned vv = *(const unsigned*)&yt[w][2 * l];
  ((unsigned*)(ymt + pbase))[l] = vv;
}

// ---------------------------------------------------------------- transpose ymt[b][d][t] -> comb[b][t][512 + d] (stride NC)
__global__ __launch_bounds__(256) void transpose_ym(
    const ushort* __restrict__ ymt, ushort* __restrict__ comb)
{
  __shared__ ushort tile[64][72];
  int tid = threadIdx.x;
  int bx = blockIdx.x;          // d-tile (DIN/64 = 16)
  int by = blockIdx.y;          // t-tile (LL/64 = 32)
  int b  = blockIdx.z;
  int r = tid >> 2, c16 = (tid & 3) * 16;
  const ushort* src = ymt + ((size_t)(b * DIN + bx * 64 + r)) * LL + by * 64 + c16;
  *(uint4*)&tile[r][c16]     = *(const uint4*)src;
  *(uint4*)&tile[r][c16 + 8] = *(const uint4*)(src + 8);
  __syncthreads();
  ushort tmp[16];
  #pragma unroll
  for (int j = 0; j < 16; j++) tmp[j] = tile[c16 + j][r];
  ushort* dst = comb + ((size_t)(b * LL + by * 64 + r)) * NC + DD + bx * 64 + c16;
  *(uint4*)dst       = *(uint4*)&tmp[0];
  *(uint4*)(dst + 8) = *(uint4*)&tmp[8];
}

// ---------------------------------------------------------------- residual + LayerNorm (x + combined attn+mamba)
__global__ __launch_bounds__(256) void residual_ln(
    const float* __restrict__ x, const float* __restrict__ so,
    const float* __restrict__ lw, const float* __restrict__ lb,
    float* __restrict__ out)
{
  int row = blockIdx.x * 4 + (threadIdx.x >> 6);
  int l = threadIdx.x & 63;
  size_t base = (size_t)row * DD;
  float h[8];
  float s = 0.f, s2 = 0.f;
  #pragma unroll
  for (int half = 0; half < 2; half++) {
    int c = half * 256 + l * 4;
    float4 xv = *(const float4*)(x + base + c);
    float4 sv = *(const float4*)(so + base + c);
    float* hp = h + half * 4;
    hp[0] = xv.x + sv.x;
    hp[1] = xv.y + sv.y;
    hp[2] = xv.z + sv.z;
    hp[3] = xv.w + sv.w;
    #pragma unroll
    for (int j = 0; j < 4; j++) { s += hp[j]; s2 += hp[j] * hp[j]; }
  }
  #pragma unroll
  for (int o = 1; o < 64; o <<= 1) { s += __shfl_xor(s, o); s2 += __shfl_xor(s2, o); }
  float mean = s * (1.f / DD);
  float var = s2 * (1.f / DD) - mean * mean;
  float rs = rsqrtf(var + 1e-5f);
  #pragma unroll
  for (int half = 0; half < 2; half++) {
    int c = half * 256 + l * 4;
    float4 ov;
    ov.x = (h[half*4+0] - mean) * rs * lw[c+0] + lb[c+0];
    ov.y = (h[half*4+1] - mean) * rs * lw[c+1] + lb[c+1];
    ov.z = (h[half*4+2] - mean) * rs * lw[c+2] + lb[c+2];
    ov.w = (h[half*4+3] - mean) * rs * lw[c+3] + lb[c+3];
    *(float4*)(out + base + c) = ov;
  }
}

// ---------------------------------------------------------------- host
extern "C" void kernel_launch(void* const* d_in, const int* in_sizes, int n_in,
                              void* d_out, int out_size, void* d_ws, size_t ws_size,
                              hipStream_t stream) {
  const float* x    = (const float*)d_in[0];
  const float* wq   = (const float*)d_in[1];
  const float* bq   = (const float*)d_in[2];
  const float* wk   = (const float*)d_in[3];
  const float* bk   = (const float*)d_in[4];
  const float* wv   = (const float*)d_in[5];
  const float* bv   = (const float*)d_in[6];
  const float* wo   = (const float*)d_in[7];
  const float* bo   = (const float*)d_in[8];
  const float* inw  = (const float*)d_in[9];
  const float* cw   = (const float*)d_in[10];
  const float* cb   = (const float*)d_in[11];
  const float* xpw  = (const float*)d_in[12];
  const float* dtw  = (const float*)d_in[13];
  const float* dtb  = (const float*)d_in[14];
  const float* alog = (const float*)d_in[15];
  const float* dpar = (const float*)d_in[16];
  const float* opw  = (const float*)d_in[17];
  const float* lnw  = (const float*)d_in[18];
  const float* lnb  = (const float*)d_in[19];

  char* ws = (char*)d_ws;
  size_t off = 0;
  auto alloc = [&](size_t bytes) -> void* {
    void* p = ws + off;
    off += (bytes + 255) & ~(size_t)255;
    return p;
  };

  const size_t BLD = (size_t)BL * DD;
  const size_t BLDIN = (size_t)BL * DIN;

  ushort* xf_b   = (ushort*)alloc(BLD * 2);
  ushort* wqi_b  = (ushort*)alloc((size_t)NQ * DD * 2);      // [qkv | in_proj] weights
  float*  bqi    = (float*)alloc(NQ * 4);
  ushort* xpw_b  = (ushort*)alloc(160 * DIN * 2);
  ushort* dtw_b  = (ushort*)alloc(DIN * RR * 2);
  ushort* wcomb_b= (ushort*)alloc((size_t)DD * NC * 2);
  ushort* qkvxz_b= (ushort*)alloc((size_t)BL * NQ * 2);      // 28.7 MB merged
  ushort* comb_a = (ushort*)alloc((size_t)BL * NC * 2);
  float*  sum_o  = (float*)alloc(BLD * 4);
  ushort* u_b    = (ushort*)alloc(BLDIN * 2);
  float*  dbc    = (float*)alloc((size_t)BL * 160 * 4);
  ushort* ymt_b  = (ushort*)alloc(BLDIN * 2);
  unsigned* bbp  = (unsigned*)alloc((size_t)BB * (LL / 2) * NS * 4);
  float4* bcp4   = (float4*)alloc((size_t)BB * (LL / 2) * NS * sizeof(float4));
  unsigned* dtu_p = (unsigned*)alloc(BLDIN * 4);
  unsigned* sg_p  = (unsigned*)alloc(BLDIN * 4);
  const size_t SCN = (size_t)BB * DIN * NCH * 64;
  float* carry_s = (float*)alloc(SCN * 4);

  // 1) convert inputs to bf16 (qkv + in_proj weights concatenated along N)
  CvtJobs cj;
  cj.src[0] = x;    cj.dst[0] = xf_b;                cj.n[0] = (int)BLD;
  cj.src[1] = wq;   cj.dst[1] = wqi_b;               cj.n[1] = DD * DD;
  cj.src[2] = wk;   cj.dst[2] = wqi_b + DD * DD;     cj.n[2] = DD * DD;
  cj.src[3] = wv;   cj.dst[3] = wqi_b + 2 * DD * DD; cj.n[3] = DD * DD;
  cj.src[4] = inw;  cj.dst[4] = wqi_b + 3 * DD * DD; cj.n[4] = 2 * DIN * DD;
  cj.src[5] = xpw;  cj.dst[5] = xpw_b;               cj.n[5] = 160 * DIN;
  cj.src[6] = dtw;  cj.dst[6] = dtw_b;               cj.n[6] = DIN * RR;
  cvt_multi<<<dim3(256, 7), 256, 0, stream>>>(cj);
  pack_wcomb<<<dim3((DD * NC + 255) / 256), 256, 0, stream>>>(wo, opw, bq, bk, bv, wcomb_b, bqi);

  // 2) merged qkv + in_proj projection (N=3584), global_load_lds staging
  gemm128<<<dim3(28, 32), 256, 0, stream>>>(xf_b, wqi_b, bqi, nullptr, qkvxz_b, BL, NQ, DD);

  // 3) depthwise conv + SiLU (sliding window, 8 t per thread)
  conv_silu<<<dim3(2048), 256, 0, stream>>>(qkvxz_b, cw, cb, u_b);

  // 4) fused: flash attention (512 blocks, T14 async dbuf) || x_proj GEMM (192 blocks)
  attn_xproj<<<dim3(704), 256, 0, stream>>>(qkvxz_b, comb_a, u_b, xpw_b, dbc);

  // 5) fused: dt_proj+softplus+time-major pack (1024 blocks) || pack B/C (512 blocks)
  dt_bc<<<dim3(1536), 256, 0, stream>>>(dbc, dtw_b, dtb, dpar, u_b, qkvxz_b,
                                        dtu_p, sg_p, bbp, bcp4);

  // 6) chunked selective scan: [phase1+carry fused] then phase3
  scan_p1c<<<dim3(BB * DIN), 256, 0, stream>>>(dtu_p, bbp, alog, carry_s);
  scan_phase3<<<dim3(8192), 256, 0, stream>>>(dtu_p, sg_p, bcp4, alog, carry_s, ymt_b);
  transpose_ym<<<dim3(16, 32, BB), 256, 0, stream>>>(ymt_b, comb_a);

  // 7) combined wo-proj + out_proj via 64-tile GEMM (512 blocks, full tiles)
  gemm_bt<<<dim3(8, 64), 256, 0, stream>>>(comb_a, wcomb_b, bo, sum_o, nullptr, BL, DD, NC, 0);

  // 8) residual + LayerNorm
  residual_ln<<<dim3(1024), 256, 0, stream>>>(x, sum_o, lnw, lnb, (float*)d_out);
}